// Round 1
// baseline (418.810 us; speedup 1.0000x reference)
//
#include <hip/hip_runtime.h>
#include <math.h>

// Problem constants (fixed by reference)
#define H_DIM 256
#define NHEAD 8
#define DHEAD 32
#define NB 2
#define TSEQ 2048
#define NEG_LOGIT (-4.2949673e11f)      // (-(2^32)+1) / 0.01
#define QK_SCALE 17.677669529663689f    // (1/sqrt(32)) / 0.01
#define LN_EPS 1e-5f

// ---------------- masks: sign(sum|x|) per row ----------------
__global__ __launch_bounds__(256) void mask_kernel(
    const float* __restrict__ Q, const float* __restrict__ K,
    float* __restrict__ qmask, float* __restrict__ kmask) {
  const int wid = threadIdx.x >> 6, lane = threadIdx.x & 63;
  int row = blockIdx.x * 4 + wid;             // 0 .. 2*NB*TSEQ-1
  const int total_q = NB * TSEQ;
  const float* src;
  float* dst;
  if (row < total_q) { src = Q + (size_t)row * H_DIM; dst = qmask + row; }
  else               { src = K + (size_t)(row - total_q) * H_DIM; dst = kmask + (row - total_q); }
  float4 v = *(const float4*)(src + lane * 4);
  float s = fabsf(v.x) + fabsf(v.y) + fabsf(v.z) + fabsf(v.w);
  #pragma unroll
  for (int off = 32; off > 0; off >>= 1) s += __shfl_xor(s, off);
  if (lane == 0) *dst = (s != 0.0f) ? 1.0f : 0.0f;
}

// ---------------- projection: relu(X @ W + b), head-split output ----------------
// dst layout: [NH][NB][TSEQ][DHEAD].  For V (which==2), row t==TSEQ-1 is zeroed
// (reference drops last key from the PV contraction but keeps it in softmax).
__global__ __launch_bounds__(256) void proj_kernel(
    const float* __restrict__ Q, const float* __restrict__ K, const float* __restrict__ V,
    const float* __restrict__ Wq, const float* __restrict__ bq,
    const float* __restrict__ Wk, const float* __restrict__ bk,
    const float* __restrict__ Wv, const float* __restrict__ bv,
    float* __restrict__ Qh, float* __restrict__ Kh, float* __restrict__ Vh) {
  const int which = blockIdx.z;
  const float* X    = which == 0 ? Q  : which == 1 ? K  : V;
  const float* W    = which == 0 ? Wq : which == 1 ? Wk : Wv;
  const float* bias = which == 0 ? bq : which == 1 ? bk : bv;
  float* dst        = which == 0 ? Qh : which == 1 ? Kh : Vh;

  __shared__ __align__(16) float At[16][68];   // A-tile transposed [c][row], pad to stride 68 (16B-aligned rows)
  __shared__ __align__(16) float Ws[16][64];   // W-tile natural [c][j]

  const int tid = threadIdx.x;
  const int ty = tid >> 4, tx = tid & 15;
  const int mbase = blockIdx.y * 64;
  const int jbase = blockIdx.x * 64;

  float acc[4][4] = {};
  for (int cb = 0; cb < H_DIM; cb += 16) {
    {   // A tile: 64 rows x 16 cols, one float4 per thread, transposed store
      int row = tid >> 2, cq = tid & 3;
      float4 a = *(const float4*)(X + (size_t)(mbase + row) * H_DIM + cb + cq * 4);
      At[cq * 4 + 0][row] = a.x; At[cq * 4 + 1][row] = a.y;
      At[cq * 4 + 2][row] = a.z; At[cq * 4 + 3][row] = a.w;
    }
    {   // W tile: 16 x 64, one float4 per thread
      int cc = tid >> 4, jq = tid & 15;
      float4 w = *(const float4*)(W + (size_t)(cb + cc) * H_DIM + jbase + jq * 4);
      *(float4*)&Ws[cc][jq * 4] = w;
    }
    __syncthreads();
    #pragma unroll
    for (int cc = 0; cc < 16; ++cc) {
      float4 a4 = *(const float4*)&At[cc][ty * 4];
      float4 w4 = *(const float4*)&Ws[cc][tx * 4];
      float av[4] = {a4.x, a4.y, a4.z, a4.w};
      float wv[4] = {w4.x, w4.y, w4.z, w4.w};
      #pragma unroll
      for (int r = 0; r < 4; ++r)
        #pragma unroll
        for (int c = 0; c < 4; ++c) acc[r][c] += av[r] * wv[c];
    }
    __syncthreads();
  }
  #pragma unroll
  for (int r = 0; r < 4; ++r) {
    int m = mbase + ty * 4 + r;
    int n = m >> 11, t = m & (TSEQ - 1);
    #pragma unroll
    for (int c = 0; c < 4; ++c) {
      int j = jbase + tx * 4 + c;
      float v = fmaxf(acc[r][c] + bias[j], 0.0f);
      if (which == 2 && t == TSEQ - 1) v = 0.0f;
      int h = j >> 5, d = j & 31;
      dst[(((size_t)h * NB + n) * TSEQ + t) * DHEAD + d] = v;
    }
  }
}

// ---------------- flash attention per (h, n, 64-query tile) ----------------
#define PS_STRIDE 66
__global__ __launch_bounds__(256) void attn_kernel(
    const float* __restrict__ Qh, const float* __restrict__ Kh, const float* __restrict__ Vh,
    const float* __restrict__ kmask, const float* __restrict__ qmask,
    float* __restrict__ Ctx) {
  __shared__ __align__(16) float Qt[32][68];       // Q tile transposed [d][q]
  __shared__ __align__(16) float Kt[32][68];       // K tile transposed [d][k]
  __shared__ __align__(16) float Vs[64][32];       // V tile natural   [k][d]
  __shared__ __align__(16) float Ps[64 * PS_STRIDE];

  const int tid = threadIdx.x;
  const int ty = tid >> 4, tx = tid & 15;
  const int b = blockIdx.x;
  const int qt = b & 31;            // 32 q-tiles
  const int n  = (b >> 5) & (NB - 1);
  const int h  = b >> 6;

  const float* Qbase = Qh + ((size_t)h * NB + n) * TSEQ * DHEAD;
  const float* Kbase = Kh + ((size_t)h * NB + n) * TSEQ * DHEAD;
  const float* Vbase = Vh + ((size_t)h * NB + n) * TSEQ * DHEAD;
  const float* km    = kmask + (size_t)n * TSEQ;
  const int qbase = qt * 64;

  // Q tile -> transposed LDS (once per block)
  for (int f = tid; f < 512; f += 256) {
    int q = f >> 3, dq = f & 7;
    float4 v = *(const float4*)(Qbase + (size_t)(qbase + q) * DHEAD + dq * 4);
    Qt[dq * 4 + 0][q] = v.x; Qt[dq * 4 + 1][q] = v.y;
    Qt[dq * 4 + 2][q] = v.z; Qt[dq * 4 + 3][q] = v.w;
  }

  float m_r[4], l_r[4];
  float2 o_r[4];
  #pragma unroll
  for (int r = 0; r < 4; ++r) { m_r[r] = -3.0e38f; l_r[r] = 0.0f; o_r[r] = make_float2(0.f, 0.f); }

  for (int kt = 0; kt < TSEQ; kt += 64) {
    __syncthreads();   // previous PV readers done (also covers Q-tile store on iter 0)
    for (int f = tid; f < 512; f += 256) {
      int k = f >> 3, dq = f & 7;
      float4 kv = *(const float4*)(Kbase + (size_t)(kt + k) * DHEAD + dq * 4);
      Kt[dq * 4 + 0][k] = kv.x; Kt[dq * 4 + 1][k] = kv.y;
      Kt[dq * 4 + 2][k] = kv.z; Kt[dq * 4 + 3][k] = kv.w;
      float4 vv = *(const float4*)(Vbase + (size_t)(kt + k) * DHEAD + dq * 4);
      *(float4*)&Vs[k][dq * 4] = vv;
    }
    __syncthreads();

    // S = Q K^T for this 64x64 tile; thread owns rows ty*4..+4, cols tx*4..+4
    float s[4][4] = {};
    #pragma unroll
    for (int kk = 0; kk < 32; ++kk) {
      float4 q4 = *(const float4*)&Qt[kk][ty * 4];
      float4 k4 = *(const float4*)&Kt[kk][tx * 4];
      float qv[4] = {q4.x, q4.y, q4.z, q4.w};
      float kv[4] = {k4.x, k4.y, k4.z, k4.w};
      #pragma unroll
      for (int r = 0; r < 4; ++r)
        #pragma unroll
        for (int c = 0; c < 4; ++c) s[r][c] += qv[r] * kv[c];
    }
    float kmv[4];
    #pragma unroll
    for (int c = 0; c < 4; ++c) kmv[c] = km[kt + tx * 4 + c];

    // online softmax (rows shared by 16 consecutive lanes -> xor-shuffle reduce)
    #pragma unroll
    for (int r = 0; r < 4; ++r) {
      float lg[4];
      #pragma unroll
      for (int c = 0; c < 4; ++c)
        lg[c] = (kmv[c] != 0.0f) ? s[r][c] * QK_SCALE : NEG_LOGIT;
      float mx = fmaxf(fmaxf(lg[0], lg[1]), fmaxf(lg[2], lg[3]));
      #pragma unroll
      for (int off = 1; off < 16; off <<= 1) mx = fmaxf(mx, __shfl_xor(mx, off));
      float mnew = fmaxf(m_r[r], mx);
      float alpha = __expf(m_r[r] - mnew);
      m_r[r] = mnew;
      float p[4], rs = 0.0f;
      #pragma unroll
      for (int c = 0; c < 4; ++c) { p[c] = __expf(lg[c] - mnew); rs += p[c]; }
      #pragma unroll
      for (int off = 1; off < 16; off <<= 1) rs += __shfl_xor(rs, off);
      l_r[r] = l_r[r] * alpha + rs;
      o_r[r].x *= alpha; o_r[r].y *= alpha;
      int i = ty * 4 + r;
      #pragma unroll
      for (int c = 0; c < 4; ++c) Ps[i * PS_STRIDE + tx * 4 + c] = p[c];
    }
    __syncthreads();

    // O += P V ; thread owns rows ty*4..+4, d = tx*2..+2
    #pragma unroll 4
    for (int k = 0; k < 64; ++k) {
      float2 v = *(const float2*)&Vs[k][tx * 2];
      #pragma unroll
      for (int r = 0; r < 4; ++r) {
        float p = Ps[(ty * 4 + r) * PS_STRIDE + k];
        o_r[r].x += p * v.x;
        o_r[r].y += p * v.y;
      }
    }
  }

  // epilogue: normalize, apply query mask, write ctx in [n][q][h*D+d] layout
  #pragma unroll
  for (int r = 0; r < 4; ++r) {
    int q = qbase + ty * 4 + r;
    float inv = 1.0f / l_r[r];
    float qm = qmask[(size_t)n * TSEQ + q];
    float2 st = make_float2(o_r[r].x * inv * qm, o_r[r].y * inv * qm);
    *(float2*)&Ctx[((size_t)n * TSEQ + q) * H_DIM + h * DHEAD + tx * 2] = st;
  }
}

// ---------------- layernorm + weight output ----------------
__global__ __launch_bounds__(256) void ln_kernel(
    const float* __restrict__ Ctx, const float* __restrict__ gamma,
    const float* __restrict__ beta, const float* __restrict__ qmask,
    float* __restrict__ out, float* __restrict__ wout) {
  const int wid = threadIdx.x >> 6, lane = threadIdx.x & 63;
  const int row = blockIdx.x * 4 + wid;       // NB*TSEQ rows
  const float* src = Ctx + (size_t)row * H_DIM;
  float4 x = *(const float4*)(src + lane * 4);
  float s = x.x + x.y + x.z + x.w;
  #pragma unroll
  for (int off = 32; off > 0; off >>= 1) s += __shfl_xor(s, off);
  float mu = s * (1.0f / H_DIM);
  float dx0 = x.x - mu, dx1 = x.y - mu, dx2 = x.z - mu, dx3 = x.w - mu;
  float sq = dx0 * dx0 + dx1 * dx1 + dx2 * dx2 + dx3 * dx3;
  #pragma unroll
  for (int off = 32; off > 0; off >>= 1) sq += __shfl_xor(sq, off);
  float rstd = rsqrtf(sq * (1.0f / H_DIM) + LN_EPS);
  float4 g = *(const float4*)(gamma + lane * 4);
  float4 bb = *(const float4*)(beta + lane * 4);
  float4 y;
  y.x = dx0 * rstd * g.x + bb.x;
  y.y = dx1 * rstd * g.y + bb.y;
  y.z = dx2 * rstd * g.z + bb.z;
  y.w = dx3 * rstd * g.w + bb.w;
  *(float4*)(out + (size_t)row * H_DIM + lane * 4) = y;
  // weight[n,q] = qmask * mean over (h,k) of attn = qmask / TSEQ (softmax sums to 1)
  if (lane == 0) wout[row] = qmask[row] * (1.0f / TSEQ);
}

extern "C" void kernel_launch(void* const* d_in, const int* in_sizes, int n_in,
                              void* d_out, int out_size, void* d_ws, size_t ws_size,
                              hipStream_t stream) {
  const float* Q  = (const float*)d_in[0];
  const float* K  = (const float*)d_in[1];
  const float* V  = (const float*)d_in[2];
  const float* Wq = (const float*)d_in[3];
  const float* bq = (const float*)d_in[4];
  const float* Wk = (const float*)d_in[5];
  const float* bk = (const float*)d_in[6];
  const float* Wv = (const float*)d_in[7];
  const float* bv = (const float*)d_in[8];
  const float* gamma = (const float*)d_in[9];
  const float* beta  = (const float*)d_in[10];

  float* ws = (float*)d_ws;
  const size_t per = (size_t)NHEAD * NB * TSEQ * DHEAD;   // 1,048,576 floats
  float* Qh = ws;
  float* Kh = Qh + per;
  float* Vh = Kh + per;
  float* Ctx = Vh + per;                                  // [NB][TSEQ][H]
  float* qmask = Ctx + (size_t)NB * TSEQ * H_DIM;
  float* kmask = qmask + (size_t)NB * TSEQ;

  float* out  = (float*)d_out;
  float* wout = out + (size_t)NB * TSEQ * H_DIM;

  hipLaunchKernelGGL(mask_kernel, dim3(2 * NB * TSEQ / 4), dim3(256), 0, stream,
                     Q, K, qmask, kmask);
  hipLaunchKernelGGL(proj_kernel, dim3(H_DIM / 64, NB * TSEQ / 64, 3), dim3(256), 0, stream,
                     Q, K, V, Wq, bq, Wk, bk, Wv, bv, Qh, Kh, Vh);
  hipLaunchKernelGGL(attn_kernel, dim3(NHEAD * NB * (TSEQ / 64)), dim3(256), 0, stream,
                     Qh, Kh, Vh, kmask, qmask, Ctx);
  hipLaunchKernelGGL(ln_kernel, dim3(NB * TSEQ / 4), dim3(256), 0, stream,
                     Ctx, gamma, beta, qmask, out, wout);
}

// Round 2
// 187.459 us; speedup vs baseline: 2.2341x; 2.2341x over previous
//
#include <hip/hip_runtime.h>
#include <math.h>

// Problem constants (fixed by reference)
#define H_DIM 256
#define NHEAD 8
#define DHEAD 32
#define NB 2
#define TSEQ 2048
#define NEG_LOGIT (-4.2949673e11f)      // (-(2^32)+1) / 0.01
#define QK_SCALE 17.677669529663689f    // (1/sqrt(32)) / 0.01
#define LN_EPS 1e-5f

typedef _Float16 half8 __attribute__((ext_vector_type(8)));
typedef float f32x4 __attribute__((ext_vector_type(4)));

__device__ __forceinline__ f32x4 mfma16(half8 a, half8 b, f32x4 c) {
  return __builtin_amdgcn_mfma_f32_16x16x32_f16(a, b, c, 0, 0, 0);
}

// ---------------- masks: sign(sum|x|) per row ----------------
__global__ __launch_bounds__(256) void mask_kernel(
    const float* __restrict__ Q, const float* __restrict__ K,
    float* __restrict__ qmask, float* __restrict__ kmask) {
  const int wid = threadIdx.x >> 6, lane = threadIdx.x & 63;
  int row = blockIdx.x * 4 + wid;             // 0 .. 2*NB*TSEQ-1
  const int total_q = NB * TSEQ;
  const float* src;
  float* dst;
  if (row < total_q) { src = Q + (size_t)row * H_DIM; dst = qmask + row; }
  else               { src = K + (size_t)(row - total_q) * H_DIM; dst = kmask + (row - total_q); }
  float4 v = *(const float4*)(src + lane * 4);
  float s = fabsf(v.x) + fabsf(v.y) + fabsf(v.z) + fabsf(v.w);
  #pragma unroll
  for (int off = 32; off > 0; off >>= 1) s += __shfl_xor(s, off);
  if (lane == 0) *dst = (s != 0.0f) ? 1.0f : 0.0f;
}

// ---------------- projection: relu(X @ W + b), head-split output ----------------
// dst layout: [NH][NB][TSEQ][DHEAD].  For V (which==2), row t==TSEQ-1 is zeroed
// (reference drops last key from the PV contraction but keeps it in softmax).
__global__ __launch_bounds__(256) void proj_kernel(
    const float* __restrict__ Q, const float* __restrict__ K, const float* __restrict__ V,
    const float* __restrict__ Wq, const float* __restrict__ bq,
    const float* __restrict__ Wk, const float* __restrict__ bk,
    const float* __restrict__ Wv, const float* __restrict__ bv,
    float* __restrict__ Qh, float* __restrict__ Kh, float* __restrict__ Vh) {
  const int which = blockIdx.z;
  const float* X    = which == 0 ? Q  : which == 1 ? K  : V;
  const float* W    = which == 0 ? Wq : which == 1 ? Wk : Wv;
  const float* bias = which == 0 ? bq : which == 1 ? bk : bv;
  float* dst        = which == 0 ? Qh : which == 1 ? Kh : Vh;

  __shared__ __align__(16) float At[16][68];
  __shared__ __align__(16) float Ws[16][64];

  const int tid = threadIdx.x;
  const int ty = tid >> 4, tx = tid & 15;
  const int mbase = blockIdx.y * 64;
  const int jbase = blockIdx.x * 64;

  float acc[4][4] = {};
  for (int cb = 0; cb < H_DIM; cb += 16) {
    {
      int row = tid >> 2, cq = tid & 3;
      float4 a = *(const float4*)(X + (size_t)(mbase + row) * H_DIM + cb + cq * 4);
      At[cq * 4 + 0][row] = a.x; At[cq * 4 + 1][row] = a.y;
      At[cq * 4 + 2][row] = a.z; At[cq * 4 + 3][row] = a.w;
    }
    {
      int cc = tid >> 4, jq = tid & 15;
      float4 w = *(const float4*)(W + (size_t)(cb + cc) * H_DIM + jbase + jq * 4);
      *(float4*)&Ws[cc][jq * 4] = w;
    }
    __syncthreads();
    #pragma unroll
    for (int cc = 0; cc < 16; ++cc) {
      float4 a4 = *(const float4*)&At[cc][ty * 4];
      float4 w4 = *(const float4*)&Ws[cc][tx * 4];
      float av[4] = {a4.x, a4.y, a4.z, a4.w};
      float wv[4] = {w4.x, w4.y, w4.z, w4.w};
      #pragma unroll
      for (int r = 0; r < 4; ++r)
        #pragma unroll
        for (int c = 0; c < 4; ++c) acc[r][c] += av[r] * wv[c];
    }
    __syncthreads();
  }
  #pragma unroll
  for (int r = 0; r < 4; ++r) {
    int m = mbase + ty * 4 + r;
    int n = m >> 11, t = m & (TSEQ - 1);
    #pragma unroll
    for (int c = 0; c < 4; ++c) {
      int j = jbase + tx * 4 + c;
      float v = fmaxf(acc[r][c] + bias[j], 0.0f);
      if (which == 2 && t == TSEQ - 1) v = 0.0f;
      int h = j >> 5, d = j & 31;
      dst[(((size_t)h * NB + n) * TSEQ + t) * DHEAD + d] = v;
    }
  }
}

// ---------------- MFMA flash attention per (h, n, 64-query tile) ----------------
// Split-fp16 QK^T (3 MFMAs per 16x16 S-tile, fp32-quality logits), fp16 PV.
// K/V staged to fragment-packed LDS (lane-linear b128); P via per-wave LDS.
__global__ __launch_bounds__(256) void attn_kernel(
    const float* __restrict__ Qh, const float* __restrict__ Kh, const float* __restrict__ Vh,
    const float* __restrict__ kmask, const float* __restrict__ qmask,
    float* __restrict__ Ctx) {
  __shared__ __align__(16) half8 KfH[256];            // K hi frags: [f16tile][64 lanes]
  __shared__ __align__(16) half8 KfL[256];            // K lo frags
  __shared__ __align__(16) half8 Vf[256];             // V frags: [(c*2+h)][64 lanes]
  __shared__ __align__(16) _Float16 Pbuf[4][16][72];  // per-wave P, row stride 72 halves

  const int tid = threadIdx.x;
  const int w = tid >> 6, lane = tid & 63;
  const int l15 = lane & 15, quad = lane >> 4;

  // XCD swizzle: blocks with same (h,n) land on the same XCD (b mod 8)
  const int b = blockIdx.x;
  const int g  = ((b & 7) << 1) | ((b >> 3) & 1);   // (h,n) group 0..15
  const int qt = b >> 4;                             // q-tile 0..31
  const int h = g >> 1, n = g & 1;

  const float* Qbase = Qh + ((size_t)h * NB + n) * TSEQ * DHEAD;
  const float* Kbase = Kh + ((size_t)h * NB + n) * TSEQ * DHEAD;
  const float* Vbase = Vh + ((size_t)h * NB + n) * TSEQ * DHEAD;
  const float* kmp   = kmask + (size_t)n * TSEQ;
  const int qbase = qt * 64;

  // per-wave Q fragment (A-operand): q = qbase + w*16 + l15, d = quad*8..+8
  half8 qhi, qlo;
  {
    const float* qp = Qbase + (size_t)(qbase + w * 16 + l15) * DHEAD + quad * 8;
    #pragma unroll
    for (int i = 0; i < 8; ++i) {
      float x = qp[i];
      _Float16 hi = (_Float16)x;
      qhi[i] = hi;
      qlo[i] = (_Float16)(x - (float)hi);
    }
  }

  float m_r[4], l_r[4];
  f32x4 O[2];
  #pragma unroll
  for (int r = 0; r < 4; ++r) { m_r[r] = -3.0e38f; l_r[r] = 0.0f; }
  O[0] = (f32x4){0.f, 0.f, 0.f, 0.f};
  O[1] = (f32x4){0.f, 0.f, 0.f, 0.f};

  const int kr = tid >> 2, kdc = tid & 3;    // K staging: row, d-chunk
  const int vd = tid & 31, vkg = tid >> 5;   // V staging: d-col, key-group

  for (int kt = 0; kt < TSEQ; kt += 64) {
    __syncthreads();   // all waves done reading frags of previous tile
    {
      // K tile 64x32 -> hi/lo frag-packed LDS
      const float* kp = Kbase + (size_t)(kt + kr) * DHEAD + kdc * 8;
      half8 hi8, lo8;
      #pragma unroll
      for (int i = 0; i < 8; ++i) {
        float x = kp[i];
        _Float16 hi = (_Float16)x;
        hi8[i] = hi;
        lo8[i] = (_Float16)(x - (float)hi);
      }
      int kslot = ((kr >> 4) << 6) | (kdc << 4) | (kr & 15);
      KfH[kslot] = hi8;
      KfL[kslot] = lo8;
      // V tile 64x32 -> transposed frag-packed LDS (8 coalesced dword loads)
      const float* vp = Vbase + (size_t)(kt + vkg * 8) * DHEAD + vd;
      half8 v8;
      #pragma unroll
      for (int j = 0; j < 8; ++j) v8[j] = (_Float16)vp[j * DHEAD];
      int vslot = (((vkg >> 2) << 1) | (vd >> 4)) << 6 | ((vkg & 3) << 4) | (vd & 15);
      Vf[vslot] = v8;
    }
    __syncthreads();

    // S = Q K^T (split-fp16: hi*hi + hi*lo + lo*hi)
    f32x4 S[4];
    #pragma unroll
    for (int f = 0; f < 4; ++f) {
      half8 bh = KfH[(f << 6) | lane];
      half8 bl = KfL[(f << 6) | lane];
      f32x4 acc = (f32x4){0.f, 0.f, 0.f, 0.f};
      acc = mfma16(qhi, bh, acc);
      acc = mfma16(qhi, bl, acc);
      acc = mfma16(qlo, bh, acc);
      S[f] = acc;
    }
    float kmf[4];
    #pragma unroll
    for (int f = 0; f < 4; ++f) kmf[f] = kmp[kt + (f << 4) + l15];

    // online softmax; C-layout rows = quad*4 + r, cols = f*16 + l15
    #pragma unroll
    for (int r = 0; r < 4; ++r) {
      float lg[4];
      #pragma unroll
      for (int f = 0; f < 4; ++f)
        lg[f] = (kmf[f] != 0.0f) ? S[f][r] * QK_SCALE : NEG_LOGIT;
      float mx = fmaxf(fmaxf(lg[0], lg[1]), fmaxf(lg[2], lg[3]));
      #pragma unroll
      for (int off = 1; off < 16; off <<= 1) mx = fmaxf(mx, __shfl_xor(mx, off));
      float mnew = fmaxf(m_r[r], mx);
      float alpha = __expf(m_r[r] - mnew);
      m_r[r] = mnew;
      float p[4], rs = 0.0f;
      #pragma unroll
      for (int f = 0; f < 4; ++f) { p[f] = __expf(lg[f] - mnew); rs += p[f]; }
      #pragma unroll
      for (int off = 1; off < 16; off <<= 1) rs += __shfl_xor(rs, off);
      l_r[r] = l_r[r] * alpha + rs;
      O[0][r] *= alpha;
      O[1][r] *= alpha;
      int row = (quad << 2) + r;
      #pragma unroll
      for (int f = 0; f < 4; ++f)
        Pbuf[w][row][(f << 4) + l15] = (_Float16)p[f];
    }
    // in-wave LDS RAW: drain DS queue before reading P as A-fragments
    asm volatile("s_waitcnt lgkmcnt(0)" ::: "memory");

    // O += P V  (P A-frags from LDS, V B-frags from LDS)
    #pragma unroll
    for (int c = 0; c < 2; ++c) {
      half8 pa = *(const half8*)&Pbuf[w][l15][(c << 5) + (quad << 3)];
      O[0] = mfma16(pa, Vf[((c << 1) | 0) << 6 | lane], O[0]);
      O[1] = mfma16(pa, Vf[((c << 1) | 1) << 6 | lane], O[1]);
    }
  }

  // epilogue: normalize, query mask, write ctx [n][q][h*32 + d]
  #pragma unroll
  for (int r = 0; r < 4; ++r) {
    int q = qbase + w * 16 + (quad << 2) + r;
    float qm = qmask[(size_t)n * TSEQ + q];
    float inv = qm / l_r[r];
    size_t base = ((size_t)n * TSEQ + q) * H_DIM + h * DHEAD;
    Ctx[base + l15]      = O[0][r] * inv;
    Ctx[base + 16 + l15] = O[1][r] * inv;
  }
}

// ---------------- layernorm + weight output ----------------
__global__ __launch_bounds__(256) void ln_kernel(
    const float* __restrict__ Ctx, const float* __restrict__ gamma,
    const float* __restrict__ beta, const float* __restrict__ qmask,
    float* __restrict__ out, float* __restrict__ wout) {
  const int wid = threadIdx.x >> 6, lane = threadIdx.x & 63;
  const int row = blockIdx.x * 4 + wid;
  const float* src = Ctx + (size_t)row * H_DIM;
  float4 x = *(const float4*)(src + lane * 4);
  float s = x.x + x.y + x.z + x.w;
  #pragma unroll
  for (int off = 32; off > 0; off >>= 1) s += __shfl_xor(s, off);
  float mu = s * (1.0f / H_DIM);
  float dx0 = x.x - mu, dx1 = x.y - mu, dx2 = x.z - mu, dx3 = x.w - mu;
  float sq = dx0 * dx0 + dx1 * dx1 + dx2 * dx2 + dx3 * dx3;
  #pragma unroll
  for (int off = 32; off > 0; off >>= 1) sq += __shfl_xor(sq, off);
  float rstd = rsqrtf(sq * (1.0f / H_DIM) + LN_EPS);
  float4 g = *(const float4*)(gamma + lane * 4);
  float4 bb = *(const float4*)(beta + lane * 4);
  float4 y;
  y.x = dx0 * rstd * g.x + bb.x;
  y.y = dx1 * rstd * g.y + bb.y;
  y.z = dx2 * rstd * g.z + bb.z;
  y.w = dx3 * rstd * g.w + bb.w;
  *(float4*)(out + (size_t)row * H_DIM + lane * 4) = y;
  if (lane == 0) wout[row] = qmask[row] * (1.0f / TSEQ);
}

extern "C" void kernel_launch(void* const* d_in, const int* in_sizes, int n_in,
                              void* d_out, int out_size, void* d_ws, size_t ws_size,
                              hipStream_t stream) {
  const float* Q  = (const float*)d_in[0];
  const float* K  = (const float*)d_in[1];
  const float* V  = (const float*)d_in[2];
  const float* Wq = (const float*)d_in[3];
  const float* bq = (const float*)d_in[4];
  const float* Wk = (const float*)d_in[5];
  const float* bk = (const float*)d_in[6];
  const float* Wv = (const float*)d_in[7];
  const float* bv = (const float*)d_in[8];
  const float* gamma = (const float*)d_in[9];
  const float* beta  = (const float*)d_in[10];

  float* ws = (float*)d_ws;
  const size_t per = (size_t)NHEAD * NB * TSEQ * DHEAD;   // 1,048,576 floats
  float* Qh = ws;
  float* Kh = Qh + per;
  float* Vh = Kh + per;
  float* Ctx = Vh + per;                                  // [NB][TSEQ][H]
  float* qmask = Ctx + (size_t)NB * TSEQ * H_DIM;
  float* kmask = qmask + (size_t)NB * TSEQ;

  float* out  = (float*)d_out;
  float* wout = out + (size_t)NB * TSEQ * H_DIM;

  hipLaunchKernelGGL(mask_kernel, dim3(2 * NB * TSEQ / 4), dim3(256), 0, stream,
                     Q, K, qmask, kmask);
  hipLaunchKernelGGL(proj_kernel, dim3(H_DIM / 64, NB * TSEQ / 64, 3), dim3(256), 0, stream,
                     Q, K, V, Wq, bq, Wk, bk, Wv, bv, Qh, Kh, Vh);
  hipLaunchKernelGGL(attn_kernel, dim3(NHEAD * NB * (TSEQ / 64)), dim3(256), 0, stream,
                     Qh, Kh, Vh, kmask, qmask, Ctx);
  hipLaunchKernelGGL(ln_kernel, dim3(NB * TSEQ / 4), dim3(256), 0, stream,
                     Ctx, gamma, beta, qmask, out, wout);
}

// Round 4
// 153.386 us; speedup vs baseline: 2.7304x; 1.2221x over previous
//
#include <hip/hip_runtime.h>
#include <math.h>

// Problem constants (fixed by reference)
#define H_DIM 256
#define NHEAD 8
#define DHEAD 32
#define NB 2
#define TSEQ 2048
#define LN_EPS 1e-5f

// softmax in exp2 domain: logit2 = s * (100/sqrt(32)) * log2(e)
#define QK2_SCALE 25.503486f
#define NEG2 (-6.2e11f)          // NEG/0.01*log2e ~ -6.196e11; any huge negative -> exp2 = 0

typedef _Float16 half8 __attribute__((ext_vector_type(8)));
typedef float f32x4 __attribute__((ext_vector_type(4)));

__device__ __forceinline__ f32x4 mfma16(half8 a, half8 b, f32x4 c) {
  return __builtin_amdgcn_mfma_f32_16x16x32_f16(a, b, c, 0, 0, 0);
}
__device__ __forceinline__ float exp2fast(float x) {
  return __builtin_amdgcn_exp2f(x);
}

// ---------------- masks: sign(sum|x|) per row ----------------
__global__ __launch_bounds__(256) void mask_kernel(
    const float* __restrict__ Q, const float* __restrict__ K,
    float* __restrict__ qmask, float* __restrict__ kmask) {
  const int wid = threadIdx.x >> 6, lane = threadIdx.x & 63;
  int row = blockIdx.x * 4 + wid;             // 0 .. 2*NB*TSEQ-1
  const int total_q = NB * TSEQ;
  const float* src;
  float* dst;
  if (row < total_q) { src = Q + (size_t)row * H_DIM; dst = qmask + row; }
  else               { src = K + (size_t)(row - total_q) * H_DIM; dst = kmask + (row - total_q); }
  float4 v = *(const float4*)(src + lane * 4);
  float s = fabsf(v.x) + fabsf(v.y) + fabsf(v.z) + fabsf(v.w);
  #pragma unroll
  for (int off = 32; off > 0; off >>= 1) s += __shfl_xor(s, off);
  if (lane == 0) *dst = (s != 0.0f) ? 1.0f : 0.0f;
}

// ---------------- W pre-pack: fp32 W -> hi/lo f16 B-fragment layout ----------------
// slot = ((which*8 + s)*16 + fg)*64 + lane; lane=(quad=d..,l15); frag holds
// B[k = s*32 + quad*8 + jj][j = fg*16 + l15]
__global__ __launch_bounds__(256) void prepack_kernel(
    const float* __restrict__ Wq, const float* __restrict__ Wk, const float* __restrict__ Wv,
    half8* __restrict__ WpkHi, half8* __restrict__ WpkLo) {
  int slot = blockIdx.x * 256 + threadIdx.x;      // 0 .. 24575
  int lane = slot & 63;
  int fg = (slot >> 6) & 15;
  int s  = (slot >> 10) & 7;
  int which = slot >> 13;
  const float* W = which == 0 ? Wq : which == 1 ? Wk : Wv;
  int j  = fg * 16 + (lane & 15);
  int kb = s * 32 + (lane >> 4) * 8;
  half8 hi, lo;
  #pragma unroll
  for (int jj = 0; jj < 8; ++jj) {
    float x = W[(size_t)(kb + jj) * H_DIM + j];
    _Float16 h = (_Float16)x;
    hi[jj] = h;
    lo[jj] = (_Float16)(x - (float)h);
  }
  WpkHi[slot] = hi;
  WpkLo[slot] = lo;
}

// ---------------- projection: relu(X @ W + b) via split-fp16 MFMA ----------------
// No LDS, no barriers. A (X rows) converted in-reg; B frags loaded pre-packed.
// Output head-split fp32 [NH][NB][TSEQ][DHEAD]; V row t==TSEQ-1 zeroed.
__global__ __launch_bounds__(256) void proj_kernel(
    const float* __restrict__ Q, const float* __restrict__ K, const float* __restrict__ V,
    const float* __restrict__ bq, const float* __restrict__ bk, const float* __restrict__ bv,
    const half8* __restrict__ WpkHi, const half8* __restrict__ WpkLo,
    float* __restrict__ Qh, float* __restrict__ Kh, float* __restrict__ Vh) {
  const int which = blockIdx.z;
  const float* X    = which == 0 ? Q  : which == 1 ? K  : V;
  const float* bias = which == 0 ? bq : which == 1 ? bk : bv;
  float* dst        = which == 0 ? Qh : which == 1 ? Kh : Vh;

  const int tid = threadIdx.x;
  const int w = tid >> 6, lane = tid & 63;
  const int l15 = lane & 15, quad = lane >> 4;
  const int mbase = blockIdx.y * 64;
  const int nfg   = blockIdx.x * 4;     // first of 4 n-frag groups

  // A: 8 k-steps, hi/lo fragments, converted in registers
  half8 ahi[8], alo[8];
  {
    const float* xrow = X + (size_t)(mbase + w * 16 + l15) * H_DIM + quad * 8;
    #pragma unroll
    for (int s = 0; s < 8; ++s) {
      float4 a0 = *(const float4*)(xrow + s * 32);
      float4 a1 = *(const float4*)(xrow + s * 32 + 4);
      float xs[8] = {a0.x, a0.y, a0.z, a0.w, a1.x, a1.y, a1.z, a1.w};
      #pragma unroll
      for (int i = 0; i < 8; ++i) {
        _Float16 h = (_Float16)xs[i];
        ahi[s][i] = h;
        alo[s][i] = (_Float16)(xs[i] - (float)h);
      }
    }
  }

  f32x4 acc[4];
  #pragma unroll
  for (int f = 0; f < 4; ++f) acc[f] = (f32x4){0.f, 0.f, 0.f, 0.f};

  #pragma unroll
  for (int s = 0; s < 8; ++s) {
    const half8* ph = WpkHi + (((size_t)which * 8 + s) * 16 + nfg) * 64 + lane;
    const half8* pl = WpkLo + (((size_t)which * 8 + s) * 16 + nfg) * 64 + lane;
    #pragma unroll
    for (int f = 0; f < 4; ++f) {
      half8 BH = ph[f * 64];
      half8 BL = pl[f * 64];
      acc[f] = mfma16(ahi[s], BH, acc[f]);
      acc[f] = mfma16(ahi[s], BL, acc[f]);
      acc[f] = mfma16(alo[s], BH, acc[f]);
    }
  }

  // epilogue: bias + relu (+ V last-row zero), head-split store
  #pragma unroll
  for (int f = 0; f < 4; ++f) {
    int j = blockIdx.x * 64 + f * 16 + l15;
    float bj = bias[j];
    int hh = j >> 5, dd = j & 31;
    #pragma unroll
    for (int r = 0; r < 4; ++r) {
      int m = mbase + w * 16 + quad * 4 + r;
      int n = m >> 11, t = m & (TSEQ - 1);
      float val = fmaxf(acc[f][r] + bj, 0.0f);
      if (which == 2 && t == TSEQ - 1) val = 0.0f;
      dst[(((size_t)hh * NB + n) * TSEQ + t) * DHEAD + dd] = val;
    }
  }
}

// ---------------- MFMA flash attention, key-split x2 ----------------
// grid 1024: b -> (hn via low bits for XCD locality, qt, sblk). Each block does
// keys [sblk*1024, +1024). Outputs unnormalized O + per-row (m,l) partials;
// ln_kernel combines. Row-sums come free via a ones-column MFMA.
__global__ __launch_bounds__(256) void attn_kernel(
    const float* __restrict__ Qh, const float* __restrict__ Kh, const float* __restrict__ Vh,
    const float* __restrict__ kmask,
    float* __restrict__ Op, float* __restrict__ Mp, float* __restrict__ Lp) {
  __shared__ __align__(16) half8 KfH[256];
  __shared__ __align__(16) half8 KfL[256];
  __shared__ __align__(16) half8 Vf[256];
  __shared__ __align__(16) _Float16 Pbuf[4][16][72];

  const int tid = threadIdx.x;
  const int w = tid >> 6, lane = tid & 63;
  const int l15 = lane & 15, quad = lane >> 4;

  const int b = blockIdx.x;
  const int g    = ((b & 7) << 1) | ((b >> 3) & 1);   // (h,n) 0..15, fixed XCD
  const int qt   = (b >> 4) & 31;
  const int sblk = b >> 9;                            // key half 0/1
  const int h = g >> 1, n = g & 1;

  const float* Qbase = Qh + ((size_t)h * NB + n) * TSEQ * DHEAD;
  const float* Kbase = Kh + ((size_t)h * NB + n) * TSEQ * DHEAD;
  const float* Vbase = Vh + ((size_t)h * NB + n) * TSEQ * DHEAD;
  const float* kmp   = kmask + (size_t)n * TSEQ;
  const int qbase  = qt * 64;
  const int kstart = sblk * 1024;

  // per-wave Q fragment: q = qbase + w*16 + l15, d = quad*8..+8
  half8 qhi, qlo;
  {
    const float* qp = Qbase + (size_t)(qbase + w * 16 + l15) * DHEAD + quad * 8;
    #pragma unroll
    for (int i = 0; i < 8; ++i) {
      float x = qp[i];
      _Float16 hi = (_Float16)x;
      qhi[i] = hi;
      qlo[i] = (_Float16)(x - (float)hi);
    }
  }

  // ones B-frag: column 0 = 1 (row-sum extractor)
  half8 onesb;
  #pragma unroll
  for (int i = 0; i < 8; ++i) onesb[i] = (l15 == 0) ? (_Float16)1.0f : (_Float16)0.0f;

  float m_r[4];
  f32x4 O0, O1, Ol;
  #pragma unroll
  for (int r = 0; r < 4; ++r) m_r[r] = -1.0e38f;
  O0 = (f32x4){0.f, 0.f, 0.f, 0.f};
  O1 = (f32x4){0.f, 0.f, 0.f, 0.f};
  Ol = (f32x4){0.f, 0.f, 0.f, 0.f};

  const int kr = tid >> 2, kdc = tid & 3;
  const int vd = tid & 31, vkg = tid >> 5;

  for (int kt = kstart; kt < kstart + 1024; kt += 64) {
    __syncthreads();
    {
      const float* kp = Kbase + (size_t)(kt + kr) * DHEAD + kdc * 8;
      half8 hi8, lo8;
      #pragma unroll
      for (int i = 0; i < 8; ++i) {
        float x = kp[i];
        _Float16 hi = (_Float16)x;
        hi8[i] = hi;
        lo8[i] = (_Float16)(x - (float)hi);
      }
      int kslot = ((kr >> 4) << 6) | (kdc << 4) | (kr & 15);
      KfH[kslot] = hi8;
      KfL[kslot] = lo8;
      const float* vp = Vbase + (size_t)(kt + vkg * 8) * DHEAD + vd;
      half8 v8;
      #pragma unroll
      for (int j = 0; j < 8; ++j) v8[j] = (_Float16)vp[j * DHEAD];
      int vslot = (((vkg >> 2) << 1) | (vd >> 4)) << 6 | ((vkg & 3) << 4) | (vd & 15);
      Vf[vslot] = v8;
    }
    __syncthreads();

    // S = Q K^T (split-fp16)
    f32x4 S[4];
    #pragma unroll
    for (int f = 0; f < 4; ++f) {
      half8 bh = KfH[(f << 6) | lane];
      half8 bl = KfL[(f << 6) | lane];
      f32x4 a = (f32x4){0.f, 0.f, 0.f, 0.f};
      a = mfma16(qhi, bh, a);
      a = mfma16(qhi, bl, a);
      a = mfma16(qlo, bh, a);
      S[f] = a;
    }
    float kmf[4];
    #pragma unroll
    for (int f = 0; f < 4; ++f) kmf[f] = kmp[kt + (f << 4) + l15];

    // logits in exp2 domain
    float lg[4][4];
    #pragma unroll
    for (int r = 0; r < 4; ++r)
      #pragma unroll
      for (int f = 0; f < 4; ++f)
        lg[r][f] = (kmf[f] != 0.0f) ? S[f][r] * QK2_SCALE : NEG2;

    // interleaved 4-row max butterfly (independent chains pipeline)
    float mx[4];
    #pragma unroll
    for (int r = 0; r < 4; ++r)
      mx[r] = fmaxf(fmaxf(lg[r][0], lg[r][1]), fmaxf(lg[r][2], lg[r][3]));
    #pragma unroll
    for (int off = 1; off < 16; off <<= 1) {
      #pragma unroll
      for (int r = 0; r < 4; ++r) mx[r] = fmaxf(mx[r], __shfl_xor(mx[r], off));
    }
    float alpha[4];
    #pragma unroll
    for (int r = 0; r < 4; ++r) {
      float mnew = fmaxf(m_r[r], mx[r]);
      alpha[r] = exp2fast(m_r[r] - mnew);
      m_r[r] = mnew;
    }
    // p = exp2(lg - m), pack to LDS (f16)
    #pragma unroll
    for (int r = 0; r < 4; ++r) {
      int row = (quad << 2) + r;
      #pragma unroll
      for (int f = 0; f < 4; ++f) {
        float p = exp2fast(lg[r][f] - m_r[r]);
        Pbuf[w][row][(f << 4) + l15] = (_Float16)p;
      }
    }
    #pragma unroll
    for (int r = 0; r < 4; ++r) {
      O0[r] *= alpha[r];
      O1[r] *= alpha[r];
      Ol[r] *= alpha[r];
    }
    // in-wave LDS RAW: drain DS queue before reading P as A-fragments
    asm volatile("s_waitcnt lgkmcnt(0)" ::: "memory");

    // O += P V ; l-column via ones-frag
    #pragma unroll
    for (int c = 0; c < 2; ++c) {
      half8 pa = *(const half8*)&Pbuf[w][l15][(c << 5) + (quad << 3)];
      O0 = mfma16(pa, Vf[((c << 1) | 0) << 6 | lane], O0);
      O1 = mfma16(pa, Vf[((c << 1) | 1) << 6 | lane], O1);
      Ol = mfma16(pa, onesb, Ol);
    }
  }

  // epilogue: store unnormalized partials (+ m,l from col-0 lanes)
  #pragma unroll
  for (int r = 0; r < 4; ++r) {
    int q = qbase + w * 16 + (quad << 2) + r;
    size_t idx = ((size_t)(sblk * 16 + g) * TSEQ + q) * DHEAD;
    Op[idx + l15]      = O0[r];
    Op[idx + 16 + l15] = O1[r];
    if (l15 == 0) {
      Mp[(size_t)(sblk * 16 + g) * TSEQ + q] = m_r[r];
      Lp[(size_t)(sblk * 16 + g) * TSEQ + q] = Ol[r];
    }
  }
}

// ---------------- fused combine + layernorm + weight ----------------
__global__ __launch_bounds__(256) void ln_kernel(
    const float* __restrict__ Op, const float* __restrict__ Mp, const float* __restrict__ Lp,
    const float* __restrict__ gamma, const float* __restrict__ beta,
    const float* __restrict__ qmask,
    float* __restrict__ out, float* __restrict__ wout) {
  const int wid = threadIdx.x >> 6, lane = threadIdx.x & 63;
  const int row = blockIdx.x * 4 + wid;      // (n,q)
  const int n = row >> 11, q = row & (TSEQ - 1);
  const int hh = lane >> 3;                  // head for this lane's 4 elements
  const int hn = hh * NB + n;
  const int dbase = (lane & 7) * 4;

  size_t i1 = ((size_t)(0 * 16 + hn) * TSEQ + q) * DHEAD + dbase;
  size_t i2 = ((size_t)(1 * 16 + hn) * TSEQ + q) * DHEAD + dbase;
  float4 P1 = *(const float4*)(Op + i1);
  float4 P2 = *(const float4*)(Op + i2);
  size_t s1 = (size_t)(0 * 16 + hn) * TSEQ + q;
  size_t s2 = (size_t)(1 * 16 + hn) * TSEQ + q;
  float m1 = Mp[s1], m2 = Mp[s2];
  float l1 = Lp[s1], l2 = Lp[s2];
  float mm = fmaxf(m1, m2);
  float a1 = exp2fast(m1 - mm), a2 = exp2fast(m2 - mm);
  float qm = qmask[row];
  float inv = qm / (l1 * a1 + l2 * a2);

  float4 x;
  x.x = (P1.x * a1 + P2.x * a2) * inv;
  x.y = (P1.y * a1 + P2.y * a2) * inv;
  x.z = (P1.z * a1 + P2.z * a2) * inv;
  x.w = (P1.w * a1 + P2.w * a2) * inv;

  float s = x.x + x.y + x.z + x.w;
  #pragma unroll
  for (int off = 32; off > 0; off >>= 1) s += __shfl_xor(s, off);
  float mu = s * (1.0f / H_DIM);
  float dx0 = x.x - mu, dx1 = x.y - mu, dx2 = x.z - mu, dx3 = x.w - mu;
  float sq = dx0 * dx0 + dx1 * dx1 + dx2 * dx2 + dx3 * dx3;
  #pragma unroll
  for (int off = 32; off > 0; off >>= 1) sq += __shfl_xor(sq, off);
  float rstd = rsqrtf(sq * (1.0f / H_DIM) + LN_EPS);
  float4 g = *(const float4*)(gamma + lane * 4);
  float4 bb = *(const float4*)(beta + lane * 4);
  float4 y;
  y.x = dx0 * rstd * g.x + bb.x;
  y.y = dx1 * rstd * g.y + bb.y;
  y.z = dx2 * rstd * g.z + bb.z;
  y.w = dx3 * rstd * g.w + bb.w;
  *(float4*)(out + (size_t)row * H_DIM + lane * 4) = y;
  if (lane == 0) wout[row] = qm * (1.0f / TSEQ);
}

extern "C" void kernel_launch(void* const* d_in, const int* in_sizes, int n_in,
                              void* d_out, int out_size, void* d_ws, size_t ws_size,
                              hipStream_t stream) {
  const float* Q  = (const float*)d_in[0];
  const float* K  = (const float*)d_in[1];
  const float* V  = (const float*)d_in[2];
  const float* Wq = (const float*)d_in[3];
  const float* bq = (const float*)d_in[4];
  const float* Wk = (const float*)d_in[5];
  const float* bk = (const float*)d_in[6];
  const float* Wv = (const float*)d_in[7];
  const float* bv = (const float*)d_in[8];
  const float* gamma = (const float*)d_in[9];
  const float* beta  = (const float*)d_in[10];

  float* ws = (float*)d_ws;
  const size_t per = (size_t)NHEAD * NB * TSEQ * DHEAD;   // 1,048,576 floats
  float* Qh = ws;                                   // 1M
  float* Kh = Qh + per;                             // 1M
  float* Vh = Kh + per;                             // 1M
  float* Opart = Vh + per;                          // 2M  [2][16][2048][32]
  float* Mp = Opart + 2 * per;                      // 64K [2][16][2048]
  float* Lp = Mp + 2 * 16 * TSEQ;                   // 64K
  float* qmask = Lp + 2 * 16 * TSEQ;                // 4K
  float* kmask = qmask + NB * TSEQ;                 // 4K
  half8* WpkHi = (half8*)(kmask + NB * TSEQ);       // 24576 slots * 16B
  half8* WpkLo = WpkHi + 3 * 8 * 16 * 64;

  float* out  = (float*)d_out;
  float* wout = out + (size_t)NB * TSEQ * H_DIM;

  hipLaunchKernelGGL(mask_kernel, dim3(2 * NB * TSEQ / 4), dim3(256), 0, stream,
                     Q, K, qmask, kmask);
  hipLaunchKernelGGL(prepack_kernel, dim3(96), dim3(256), 0, stream,
                     Wq, Wk, Wv, WpkHi, WpkLo);
  hipLaunchKernelGGL(proj_kernel, dim3(H_DIM / 64, NB * TSEQ / 64, 3), dim3(256), 0, stream,
                     Q, K, V, bq, bk, bv, WpkHi, WpkLo, Qh, Kh, Vh);
  hipLaunchKernelGGL(attn_kernel, dim3(NHEAD * NB * (TSEQ / 64) * 2), dim3(256), 0, stream,
                     Qh, Kh, Vh, kmask, Opart, Mp, Lp);
  hipLaunchKernelGGL(ln_kernel, dim3(NB * TSEQ / 4), dim3(256), 0, stream,
                     Opart, Mp, Lp, gamma, beta, qmask, out, wout);
}

// Round 5
// 151.539 us; speedup vs baseline: 2.7637x; 1.0122x over previous
//
#include <hip/hip_runtime.h>
#include <math.h>

// Problem constants (fixed by reference)
#define H_DIM 256
#define NHEAD 8
#define DHEAD 32
#define NB 2
#define TSEQ 2048
#define LN_EPS 1e-5f

// softmax in exp2 domain: logit2 = s * (100/sqrt(32)) * log2(e).
// QK2_SCALE is folded into the packed Q fragments (repack_kernel).
#define QK2_SCALE 25.503486f
#define NEG2 (-6.2e11f)
#define SPLIT 4                  // key-split factor
#define TILES_PER (TSEQ / 64 / SPLIT)   // 8 k-tiles per block

typedef _Float16 half8 __attribute__((ext_vector_type(8)));
typedef float f32x4 __attribute__((ext_vector_type(4)));

__device__ __forceinline__ f32x4 mfma16(half8 a, half8 b, f32x4 c) {
  return __builtin_amdgcn_mfma_f32_16x16x32_f16(a, b, c, 0, 0, 0);
}
__device__ __forceinline__ float exp2fast(float x) {
  return __builtin_amdgcn_exp2f(x);
}
// max-reduce across a 16-lane DPP row (l15 groups) — VALU pipe, no DS traffic
#define DPP_MAX4(mx, CTRL)                                                   \
  {                                                                          \
    _Pragma("unroll")                                                        \
    for (int r = 0; r < 4; ++r) {                                            \
      int t_ = __builtin_amdgcn_update_dpp(0, __float_as_int(mx[r]), CTRL,   \
                                           0xf, 0xf, false);                 \
      mx[r] = fmaxf(mx[r], __int_as_float(t_));                              \
    }                                                                        \
  }

// ---------------- masks: sign(sum|x|) per row ----------------
__global__ __launch_bounds__(256) void mask_kernel(
    const float* __restrict__ Q, const float* __restrict__ K,
    float* __restrict__ qmask, float* __restrict__ kmask) {
  const int wid = threadIdx.x >> 6, lane = threadIdx.x & 63;
  int row = blockIdx.x * 4 + wid;
  const int total_q = NB * TSEQ;
  const float* src;
  float* dst;
  if (row < total_q) { src = Q + (size_t)row * H_DIM; dst = qmask + row; }
  else               { src = K + (size_t)(row - total_q) * H_DIM; dst = kmask + (row - total_q); }
  float4 v = *(const float4*)(src + lane * 4);
  float s = fabsf(v.x) + fabsf(v.y) + fabsf(v.z) + fabsf(v.w);
  #pragma unroll
  for (int off = 32; off > 0; off >>= 1) s += __shfl_xor(s, off);
  if (lane == 0) *dst = (s != 0.0f) ? 1.0f : 0.0f;
}

// ---------------- W pre-pack: fp32 W -> hi/lo f16 B-fragment layout ----------------
__global__ __launch_bounds__(256) void prepack_kernel(
    const float* __restrict__ Wq, const float* __restrict__ Wk, const float* __restrict__ Wv,
    half8* __restrict__ WpkHi, half8* __restrict__ WpkLo) {
  int slot = blockIdx.x * 256 + threadIdx.x;
  int lane = slot & 63;
  int fg = (slot >> 6) & 15;
  int s  = (slot >> 10) & 7;
  int which = slot >> 13;
  const float* W = which == 0 ? Wq : which == 1 ? Wk : Wv;
  int j  = fg * 16 + (lane & 15);
  int kb = s * 32 + (lane >> 4) * 8;
  half8 hi, lo;
  #pragma unroll
  for (int jj = 0; jj < 8; ++jj) {
    float x = W[(size_t)(kb + jj) * H_DIM + j];
    _Float16 h = (_Float16)x;
    hi[jj] = h;
    lo[jj] = (_Float16)(x - (float)h);
  }
  WpkHi[slot] = hi;
  WpkLo[slot] = lo;
}

// ---------------- projection: relu(X @ W + b) via split-fp16 MFMA ----------------
__global__ __launch_bounds__(256) void proj_kernel(
    const float* __restrict__ Q, const float* __restrict__ K, const float* __restrict__ V,
    const float* __restrict__ bq, const float* __restrict__ bk, const float* __restrict__ bv,
    const half8* __restrict__ WpkHi, const half8* __restrict__ WpkLo,
    float* __restrict__ Qh, float* __restrict__ Kh, float* __restrict__ Vh) {
  const int which = blockIdx.z;
  const float* X    = which == 0 ? Q  : which == 1 ? K  : V;
  const float* bias = which == 0 ? bq : which == 1 ? bk : bv;
  float* dst        = which == 0 ? Qh : which == 1 ? Kh : Vh;

  const int tid = threadIdx.x;
  const int w = tid >> 6, lane = tid & 63;
  const int l15 = lane & 15, quad = lane >> 4;
  const int mbase = blockIdx.y * 64;
  const int nfg   = blockIdx.x * 4;

  half8 ahi[8], alo[8];
  {
    const float* xrow = X + (size_t)(mbase + w * 16 + l15) * H_DIM + quad * 8;
    #pragma unroll
    for (int s = 0; s < 8; ++s) {
      float4 a0 = *(const float4*)(xrow + s * 32);
      float4 a1 = *(const float4*)(xrow + s * 32 + 4);
      float xs[8] = {a0.x, a0.y, a0.z, a0.w, a1.x, a1.y, a1.z, a1.w};
      #pragma unroll
      for (int i = 0; i < 8; ++i) {
        _Float16 h = (_Float16)xs[i];
        ahi[s][i] = h;
        alo[s][i] = (_Float16)(xs[i] - (float)h);
      }
    }
  }

  f32x4 acc[4];
  #pragma unroll
  for (int f = 0; f < 4; ++f) acc[f] = (f32x4){0.f, 0.f, 0.f, 0.f};

  #pragma unroll
  for (int s = 0; s < 8; ++s) {
    const half8* ph = WpkHi + (((size_t)which * 8 + s) * 16 + nfg) * 64 + lane;
    const half8* pl = WpkLo + (((size_t)which * 8 + s) * 16 + nfg) * 64 + lane;
    #pragma unroll
    for (int f = 0; f < 4; ++f) {
      half8 BH = ph[f * 64];
      half8 BL = pl[f * 64];
      acc[f] = mfma16(ahi[s], BH, acc[f]);
      acc[f] = mfma16(ahi[s], BL, acc[f]);
      acc[f] = mfma16(alo[s], BH, acc[f]);
    }
  }

  #pragma unroll
  for (int f = 0; f < 4; ++f) {
    int j = blockIdx.x * 64 + f * 16 + l15;
    float bj = bias[j];
    int hh = j >> 5, dd = j & 31;
    #pragma unroll
    for (int r = 0; r < 4; ++r) {
      int m = mbase + w * 16 + quad * 4 + r;
      int n = m >> 11, t = m & (TSEQ - 1);
      float val = fmaxf(acc[f][r] + bj, 0.0f);
      if (which == 2 && t == TSEQ - 1) val = 0.0f;
      dst[(((size_t)hh * NB + n) * TSEQ + t) * DHEAD + dd] = val;
    }
  }
}

// ---------------- repack: fp32 head-split QKV -> MFMA fragment arrays ----------------
// Q/K: slot = f*64 + kdc*16 + krlo holds hi/lo f16 of rows[tile*64+f*16+krlo],
// d = kdc*8..+8 (Q pre-scaled by QK2_SCALE). V: transposed B-frags (8 keys of one d-col).
__global__ __launch_bounds__(256) void repack_kernel(
    const float* __restrict__ Qh, const float* __restrict__ Kh, const float* __restrict__ Vh,
    half8* __restrict__ Gqhi, half8* __restrict__ Gqlo,
    half8* __restrict__ Gkhi, half8* __restrict__ Gklo, half8* __restrict__ Gv) {
  const int tile = blockIdx.x;      // 0..31
  const int hn   = blockIdx.y;      // 0..15 (= h*NB+n)
  const int which = blockIdx.z;     // 0:Q 1:K 2:V
  const int tid = threadIdx.x;
  if (which < 2) {
    const int w = tid >> 6, lane = tid & 63;
    const int f = w, krlo = lane >> 2, kdc = lane & 3;
    const float* src = (which == 0 ? Qh : Kh) +
        ((size_t)hn * TSEQ + tile * 64 + f * 16 + krlo) * DHEAD + kdc * 8;
    float4 a0 = *(const float4*)src;
    float4 a1 = *(const float4*)(src + 4);
    float xs[8] = {a0.x, a0.y, a0.z, a0.w, a1.x, a1.y, a1.z, a1.w};
    const float sc = which == 0 ? QK2_SCALE : 1.0f;
    half8 hi, lo;
    #pragma unroll
    for (int i = 0; i < 8; ++i) {
      float x = xs[i] * sc;
      _Float16 h = (_Float16)x;
      hi[i] = h;
      lo[i] = (_Float16)(x - (float)h);
    }
    size_t di = ((size_t)hn * 32 + tile) * 256 + f * 64 + kdc * 16 + krlo;
    if (which == 0) { Gqhi[di] = hi; Gqlo[di] = lo; }
    else            { Gkhi[di] = hi; Gklo[di] = lo; }
  } else {
    const int s = tid;
    const int top = s >> 6, mid = (s >> 4) & 3, low = s & 15;
    const int c = top >> 1, hh = top & 1;
    const int vkg = c * 4 + mid, vd = hh * 16 + low;
    const float* src = Vh + ((size_t)hn * TSEQ + tile * 64 + vkg * 8) * DHEAD + vd;
    half8 v8;
    #pragma unroll
    for (int j = 0; j < 8; ++j) v8[j] = (_Float16)src[j * DHEAD];
    Gv[((size_t)hn * 32 + tile) * 256 + s] = v8;
  }
}

// ---------------- MFMA flash attention, key-split x4 ----------------
// K frags loaded global->reg (L2-hot), V double-buffered in LDS (1 barrier/tile),
// P via per-wave LDS round trip, row-max via DPP (VALU), row-sum via ones-MFMA.
__global__ __launch_bounds__(256) void attn_kernel(
    const half8* __restrict__ Gqhi, const half8* __restrict__ Gqlo,
    const half8* __restrict__ Gkhi, const half8* __restrict__ Gklo,
    const half8* __restrict__ Gv, const float* __restrict__ kmask,
    float* __restrict__ Op, float* __restrict__ Mp, float* __restrict__ Lp) {
  __shared__ __align__(16) half8 Vf[2][256];           // 8 KB, double-buffered
  __shared__ __align__(16) _Float16 Pbuf[4][16][72];   // 9216 B

  const int tid = threadIdx.x;
  const int w = tid >> 6, lane = tid & 63;
  const int l15 = lane & 15, quad = lane >> 4;

  const int b = blockIdx.x;
  const int g    = ((b & 7) << 1) | ((b >> 3) & 1);   // hn = h*2+n, XCD-pinned
  const int qt   = (b >> 4) & 31;
  const int sblk = b >> 9;                            // 0..3
  const int n = g & 1;

  const size_t fbase = (size_t)g * 32 * 256;
  const int tile0 = sblk * TILES_PER;

  half8 qhi = Gqhi[fbase + (size_t)qt * 256 + w * 64 + lane];
  half8 qlo = Gqlo[fbase + (size_t)qt * 256 + w * 64 + lane];

  const float* kmp = kmask + (size_t)n * TSEQ + sblk * (TSEQ / SPLIT);

  half8 onesb;
  #pragma unroll
  for (int i = 0; i < 8; ++i) onesb[i] = (l15 == 0) ? (_Float16)1.0f : (_Float16)0.0f;

  float m_r[4];
  f32x4 O0, O1, Ol;
  #pragma unroll
  for (int r = 0; r < 4; ++r) m_r[r] = -1.0e38f;
  O0 = (f32x4){0.f, 0.f, 0.f, 0.f};
  O1 = (f32x4){0.f, 0.f, 0.f, 0.f};
  Ol = (f32x4){0.f, 0.f, 0.f, 0.f};

  // V tile0 -> Vf[0]
  {
    half8 v0 = Gv[fbase + (size_t)tile0 * 256 + tid];
    Vf[0][tid] = v0;
  }

  for (int tt = 0; tt < TILES_PER; ++tt) {
    half8 vnext;
    if (tt < TILES_PER - 1)
      vnext = Gv[fbase + (size_t)(tile0 + tt + 1) * 256 + tid];
    __syncthreads();     // Vf[tt&1] writes visible; all reads of Vf[(tt+1)&1] done
    if (tt < TILES_PER - 1)
      Vf[(tt + 1) & 1][tid] = vnext;

    // S = Q K^T (split-fp16), K frags straight from global (L2)
    const half8* kh = Gkhi + fbase + (size_t)(tile0 + tt) * 256;
    const half8* kl = Gklo + fbase + (size_t)(tile0 + tt) * 256;
    f32x4 S[4];
    #pragma unroll
    for (int f = 0; f < 4; ++f) {
      half8 KH = kh[f * 64 + lane];
      half8 KL = kl[f * 64 + lane];
      f32x4 a = (f32x4){0.f, 0.f, 0.f, 0.f};
      a = mfma16(qlo, KH, a);
      a = mfma16(qhi, KL, a);
      a = mfma16(qhi, KH, a);
      S[f] = a;
    }
    float kmf[4];
    #pragma unroll
    for (int f = 0; f < 4; ++f) kmf[f] = kmp[tt * 64 + (f << 4) + l15];

    float lg[4][4];
    #pragma unroll
    for (int r = 0; r < 4; ++r)
      #pragma unroll
      for (int f = 0; f < 4; ++f)
        lg[r][f] = (kmf[f] != 0.0f) ? S[f][r] : NEG2;

    // row max: 4 independent DPP ror chains (VALU pipe)
    float mx[4];
    #pragma unroll
    for (int r = 0; r < 4; ++r)
      mx[r] = fmaxf(fmaxf(lg[r][0], lg[r][1]), fmaxf(lg[r][2], lg[r][3]));
    DPP_MAX4(mx, 0x128);   // row_ror:8
    DPP_MAX4(mx, 0x124);   // row_ror:4
    DPP_MAX4(mx, 0x122);   // row_ror:2
    DPP_MAX4(mx, 0x121);   // row_ror:1

    float alpha[4];
    #pragma unroll
    for (int r = 0; r < 4; ++r) {
      float mnew = fmaxf(m_r[r], mx[r]);
      alpha[r] = exp2fast(m_r[r] - mnew);
      m_r[r] = mnew;
    }
    #pragma unroll
    for (int r = 0; r < 4; ++r) {
      int row = (quad << 2) + r;
      #pragma unroll
      for (int f = 0; f < 4; ++f)
        Pbuf[w][row][(f << 4) + l15] = (_Float16)exp2fast(lg[r][f] - m_r[r]);
    }
    #pragma unroll
    for (int r = 0; r < 4; ++r) {
      O0[r] *= alpha[r];
      O1[r] *= alpha[r];
      Ol[r] *= alpha[r];
    }
    // in-wave LDS RAW: drain DS queue before reading P as A-fragments
    asm volatile("s_waitcnt lgkmcnt(0)" ::: "memory");

    const half8* vbuf = (const half8*)Vf[tt & 1];
    #pragma unroll
    for (int c = 0; c < 2; ++c) {
      half8 pa = *(const half8*)&Pbuf[w][l15][(c << 5) + (quad << 3)];
      O0 = mfma16(pa, vbuf[((c << 1) | 0) * 64 + lane], O0);
      O1 = mfma16(pa, vbuf[((c << 1) | 1) * 64 + lane], O1);
      Ol = mfma16(pa, onesb, Ol);
    }
  }

  // epilogue: unnormalized partials + (m,l)
  #pragma unroll
  for (int r = 0; r < 4; ++r) {
    int q = qt * 64 + w * 16 + (quad << 2) + r;
    size_t idx = ((size_t)(sblk * 16 + g) * TSEQ + q) * DHEAD;
    Op[idx + l15]      = O0[r];
    Op[idx + 16 + l15] = O1[r];
    if (l15 == 0) {
      Mp[(size_t)(sblk * 16 + g) * TSEQ + q] = m_r[r];
      Lp[(size_t)(sblk * 16 + g) * TSEQ + q] = Ol[r];
    }
  }
}

// ---------------- fused 4-way combine + layernorm + weight ----------------
__global__ __launch_bounds__(256) void ln_kernel(
    const float* __restrict__ Op, const float* __restrict__ Mp, const float* __restrict__ Lp,
    const float* __restrict__ gamma, const float* __restrict__ beta,
    const float* __restrict__ qmask,
    float* __restrict__ out, float* __restrict__ wout) {
  const int wid = threadIdx.x >> 6, lane = threadIdx.x & 63;
  const int row = blockIdx.x * 4 + wid;
  const int n = row >> 11, q = row & (TSEQ - 1);
  const int hh = lane >> 3;
  const int hn = hh * NB + n;
  const int dbase = (lane & 7) * 4;

  float4 P[SPLIT];
  float m[SPLIT], l[SPLIT];
  #pragma unroll
  for (int i = 0; i < SPLIT; ++i) {
    size_t si = (size_t)(i * 16 + hn) * TSEQ + q;
    P[i] = *(const float4*)(Op + si * DHEAD + dbase);
    m[i] = Mp[si];
    l[i] = Lp[si];
  }
  float mm = fmaxf(fmaxf(m[0], m[1]), fmaxf(m[2], m[3]));
  float denom = 0.f;
  float a[SPLIT];
  #pragma unroll
  for (int i = 0; i < SPLIT; ++i) { a[i] = exp2fast(m[i] - mm); denom += l[i] * a[i]; }
  float qm = qmask[row];
  float inv = qm / denom;

  float4 x = make_float4(0.f, 0.f, 0.f, 0.f);
  #pragma unroll
  for (int i = 0; i < SPLIT; ++i) {
    x.x += P[i].x * a[i]; x.y += P[i].y * a[i];
    x.z += P[i].z * a[i]; x.w += P[i].w * a[i];
  }
  x.x *= inv; x.y *= inv; x.z *= inv; x.w *= inv;

  float s = x.x + x.y + x.z + x.w;
  #pragma unroll
  for (int off = 32; off > 0; off >>= 1) s += __shfl_xor(s, off);
  float mu = s * (1.0f / H_DIM);
  float dx0 = x.x - mu, dx1 = x.y - mu, dx2 = x.z - mu, dx3 = x.w - mu;
  float sq = dx0 * dx0 + dx1 * dx1 + dx2 * dx2 + dx3 * dx3;
  #pragma unroll
  for (int off = 32; off > 0; off >>= 1) sq += __shfl_xor(sq, off);
  float rstd = rsqrtf(sq * (1.0f / H_DIM) + LN_EPS);
  float4 g = *(const float4*)(gamma + lane * 4);
  float4 bb = *(const float4*)(beta + lane * 4);
  float4 y;
  y.x = dx0 * rstd * g.x + bb.x;
  y.y = dx1 * rstd * g.y + bb.y;
  y.z = dx2 * rstd * g.z + bb.z;
  y.w = dx3 * rstd * g.w + bb.w;
  *(float4*)(out + (size_t)row * H_DIM + lane * 4) = y;
  if (lane == 0) wout[row] = qm * (1.0f / TSEQ);
}

extern "C" void kernel_launch(void* const* d_in, const int* in_sizes, int n_in,
                              void* d_out, int out_size, void* d_ws, size_t ws_size,
                              hipStream_t stream) {
  const float* Q  = (const float*)d_in[0];
  const float* K  = (const float*)d_in[1];
  const float* V  = (const float*)d_in[2];
  const float* Wq = (const float*)d_in[3];
  const float* bq = (const float*)d_in[4];
  const float* Wk = (const float*)d_in[5];
  const float* bk = (const float*)d_in[6];
  const float* Wv = (const float*)d_in[7];
  const float* bv = (const float*)d_in[8];
  const float* gamma = (const float*)d_in[9];
  const float* beta  = (const float*)d_in[10];

  float* ws = (float*)d_ws;
  const size_t perHN = (size_t)16 * TSEQ * DHEAD;    // 1,048,576 floats (all 16 hn)
  // fp32 QKV (proj->repack) and Opart (attn->ln) alias the same region:
  // attn/ln never touch the fp32 arrays, proj/repack never touch Opart.
  float* Qh = ws;
  float* Kh = Qh + perHN;
  float* Vh = Kh + perHN;
  float* Opart = ws;                                  // [SPLIT][16][TSEQ][DHEAD] = 4*perHN
  float* tail = ws + 4 * perHN;
  const size_t NFRAG = (size_t)16 * 32 * 256;         // 131072 frags per array
  half8* Gqhi = (half8*)tail;
  half8* Gqlo = Gqhi + NFRAG;
  half8* Gkhi = Gqlo + NFRAG;
  half8* Gklo = Gkhi + NFRAG;
  half8* Gv   = Gklo + NFRAG;
  float* Mp = (float*)(Gv + NFRAG);                   // [SPLIT][16][TSEQ]
  float* Lp = Mp + SPLIT * 16 * TSEQ;
  float* qmask = Lp + SPLIT * 16 * TSEQ;
  float* kmask = qmask + NB * TSEQ;
  half8* WpkHi = (half8*)(kmask + NB * TSEQ);
  half8* WpkLo = WpkHi + 24576;

  float* out  = (float*)d_out;
  float* wout = out + (size_t)NB * TSEQ * H_DIM;

  hipLaunchKernelGGL(mask_kernel, dim3(2 * NB * TSEQ / 4), dim3(256), 0, stream,
                     Q, K, qmask, kmask);
  hipLaunchKernelGGL(prepack_kernel, dim3(96), dim3(256), 0, stream,
                     Wq, Wk, Wv, WpkHi, WpkLo);
  hipLaunchKernelGGL(proj_kernel, dim3(H_DIM / 64, NB * TSEQ / 64, 3), dim3(256), 0, stream,
                     Q, K, V, bq, bk, bv, WpkHi, WpkLo, Qh, Kh, Vh);
  hipLaunchKernelGGL(repack_kernel, dim3(32, 16, 3), dim3(256), 0, stream,
                     Qh, Kh, Vh, Gqhi, Gqlo, Gkhi, Gklo, Gv);
  hipLaunchKernelGGL(attn_kernel, dim3(16 * 32 * SPLIT), dim3(256), 0, stream,
                     Gqhi, Gqlo, Gkhi, Gklo, Gv, kmask, Opart, Mp, Lp);
  hipLaunchKernelGGL(ln_kernel, dim3(NB * TSEQ / 4), dim3(256), 0, stream,
                     Opart, Mp, Lp, gamma, beta, qmask, out, wout);
}

// Round 7
// 143.785 us; speedup vs baseline: 2.9127x; 1.0539x over previous
//
#include <hip/hip_runtime.h>
#include <math.h>

// Problem constants (fixed by reference)
#define H_DIM 256
#define NHEAD 8
#define DHEAD 32
#define NB 2
#define TSEQ 2048
#define LN_EPS 1e-5f

// softmax in exp2 domain: logit2 = s * (100/sqrt(32)) * log2(e).
// QK2_SCALE is folded into the packed Q fragments (repack_kernel).
#define QK2_SCALE 25.503486f
#define SPLIT 4                         // key-split factor
#define TILES_PER (TSEQ / 64 / SPLIT)   // 8 k-tiles per block

typedef _Float16 half8 __attribute__((ext_vector_type(8)));
typedef _Float16 half2t __attribute__((ext_vector_type(2)));
typedef float f32x4 __attribute__((ext_vector_type(4)));

__device__ __forceinline__ f32x4 mfma16(half8 a, half8 b, f32x4 c) {
  return __builtin_amdgcn_mfma_f32_16x16x32_f16(a, b, c, 0, 0, 0);
}
__device__ __forceinline__ float exp2fast(float x) {
  return __builtin_amdgcn_exp2f(x);
}
__device__ __forceinline__ half2t pkrtz(float a, float b) {
  return __builtin_bit_cast(half2t, __builtin_amdgcn_cvt_pkrtz(a, b));
}

// ---------------- masks: sign(sum|x|) per row ----------------
__global__ __launch_bounds__(256) void mask_kernel(
    const float* __restrict__ Q, const float* __restrict__ K,
    float* __restrict__ qmask, float* __restrict__ kmask) {
  const int wid = threadIdx.x >> 6, lane = threadIdx.x & 63;
  int row = blockIdx.x * 4 + wid;
  const int total_q = NB * TSEQ;
  const float* src;
  float* dst;
  if (row < total_q) { src = Q + (size_t)row * H_DIM; dst = qmask + row; }
  else               { src = K + (size_t)(row - total_q) * H_DIM; dst = kmask + (row - total_q); }
  float4 v = *(const float4*)(src + lane * 4);
  float s = fabsf(v.x) + fabsf(v.y) + fabsf(v.z) + fabsf(v.w);
  #pragma unroll
  for (int off = 32; off > 0; off >>= 1) s += __shfl_xor(s, off);
  if (lane == 0) *dst = (s != 0.0f) ? 1.0f : 0.0f;
}

// ---------------- W pre-pack: fp32 W -> hi/lo f16 B-fragment layout ----------------
__global__ __launch_bounds__(256) void prepack_kernel(
    const float* __restrict__ Wq, const float* __restrict__ Wk, const float* __restrict__ Wv,
    half8* __restrict__ WpkHi, half8* __restrict__ WpkLo) {
  int slot = blockIdx.x * 256 + threadIdx.x;
  int lane = slot & 63;
  int fg = (slot >> 6) & 15;
  int s  = (slot >> 10) & 7;
  int which = slot >> 13;
  const float* W = which == 0 ? Wq : which == 1 ? Wk : Wv;
  int j  = fg * 16 + (lane & 15);
  int kb = s * 32 + (lane >> 4) * 8;
  half8 hi, lo;
  #pragma unroll
  for (int jj = 0; jj < 8; ++jj) {
    float x = W[(size_t)(kb + jj) * H_DIM + j];
    _Float16 h = (_Float16)x;
    hi[jj] = h;
    lo[jj] = (_Float16)(x - (float)h);
  }
  WpkHi[slot] = hi;
  WpkLo[slot] = lo;
}

// ---------------- projection: relu(X @ W + b) via split-fp16 MFMA ----------------
__global__ __launch_bounds__(256) void proj_kernel(
    const float* __restrict__ Q, const float* __restrict__ K, const float* __restrict__ V,
    const float* __restrict__ bq, const float* __restrict__ bk, const float* __restrict__ bv,
    const half8* __restrict__ WpkHi, const half8* __restrict__ WpkLo,
    float* __restrict__ Qh, float* __restrict__ Kh, float* __restrict__ Vh) {
  const int which = blockIdx.z;
  const float* X    = which == 0 ? Q  : which == 1 ? K  : V;
  const float* bias = which == 0 ? bq : which == 1 ? bk : bv;
  float* dst        = which == 0 ? Qh : which == 1 ? Kh : Vh;

  const int tid = threadIdx.x;
  const int w = tid >> 6, lane = tid & 63;
  const int l15 = lane & 15, quad = lane >> 4;
  const int mbase = blockIdx.y * 64;
  const int nfg   = blockIdx.x * 4;

  half8 ahi[8], alo[8];
  {
    const float* xrow = X + (size_t)(mbase + w * 16 + l15) * H_DIM + quad * 8;
    #pragma unroll
    for (int s = 0; s < 8; ++s) {
      float4 a0 = *(const float4*)(xrow + s * 32);
      float4 a1 = *(const float4*)(xrow + s * 32 + 4);
      float xs[8] = {a0.x, a0.y, a0.z, a0.w, a1.x, a1.y, a1.z, a1.w};
      #pragma unroll
      for (int i = 0; i < 8; ++i) {
        _Float16 h = (_Float16)xs[i];
        ahi[s][i] = h;
        alo[s][i] = (_Float16)(xs[i] - (float)h);
      }
    }
  }

  f32x4 acc[4];
  #pragma unroll
  for (int f = 0; f < 4; ++f) acc[f] = (f32x4){0.f, 0.f, 0.f, 0.f};

  #pragma unroll
  for (int s = 0; s < 8; ++s) {
    const half8* ph = WpkHi + (((size_t)which * 8 + s) * 16 + nfg) * 64 + lane;
    const half8* pl = WpkLo + (((size_t)which * 8 + s) * 16 + nfg) * 64 + lane;
    #pragma unroll
    for (int f = 0; f < 4; ++f) {
      half8 BH = ph[f * 64];
      half8 BL = pl[f * 64];
      acc[f] = mfma16(ahi[s], BH, acc[f]);
      acc[f] = mfma16(ahi[s], BL, acc[f]);
      acc[f] = mfma16(alo[s], BH, acc[f]);
    }
  }

  #pragma unroll
  for (int f = 0; f < 4; ++f) {
    int j = blockIdx.x * 64 + f * 16 + l15;
    float bj = bias[j];
    int hh = j >> 5, dd = j & 31;
    #pragma unroll
    for (int r = 0; r < 4; ++r) {
      int m = mbase + w * 16 + quad * 4 + r;
      int n = m >> 11, t = m & (TSEQ - 1);
      float val = fmaxf(acc[f][r] + bj, 0.0f);
      if (which == 2 && t == TSEQ - 1) val = 0.0f;
      dst[(((size_t)hh * NB + n) * TSEQ + t) * DHEAD + dd] = val;
    }
  }
}

// ---------------- repack: fp32 head-split QKV -> MFMA fragment arrays ----------------
// Q/K frags: slot f*64 + quad*16 + l15 holds rows[tile*64 + f*16 + l15], d = quad*8..+8
// (Q pre-scaled by QK2_SCALE). V: transposed frags (8 keys of one d-col), kmask-zeroed.
// z==3: AmaskF[n][tile][c][lane] = mask-row A-fragment (row0 = kmask as f16).
__global__ __launch_bounds__(256) void repack_kernel(
    const float* __restrict__ Qh, const float* __restrict__ Kh, const float* __restrict__ Vh,
    const float* __restrict__ kmask,
    half8* __restrict__ Gqhi, half8* __restrict__ Gqlo,
    half8* __restrict__ Gkhi, half8* __restrict__ Gklo, half8* __restrict__ Gv,
    half8* __restrict__ AmaskF) {
  const int tile = blockIdx.x;      // 0..31
  const int hn   = blockIdx.y;      // 0..15 (= h*NB+n)
  const int which = blockIdx.z;     // 0:Q 1:K 2:V 3:AmaskF
  const int tid = threadIdx.x;
  if (which < 2) {
    const int w = tid >> 6, lane = tid & 63;
    const int f = w, krlo = lane & 15, kdc = lane >> 4;
    const float* src = (which == 0 ? Qh : Kh) +
        ((size_t)hn * TSEQ + tile * 64 + f * 16 + krlo) * DHEAD + kdc * 8;
    float4 a0 = *(const float4*)src;
    float4 a1 = *(const float4*)(src + 4);
    float xs[8] = {a0.x, a0.y, a0.z, a0.w, a1.x, a1.y, a1.z, a1.w};
    const float sc = which == 0 ? QK2_SCALE : 1.0f;
    half8 hi, lo;
    #pragma unroll
    for (int i = 0; i < 8; ++i) {
      float x = xs[i] * sc;
      _Float16 h = (_Float16)x;
      hi[i] = h;
      lo[i] = (_Float16)(x - (float)h);
    }
    size_t di = ((size_t)hn * 32 + tile) * 256 + f * 64 + kdc * 16 + krlo;
    if (which == 0) { Gqhi[di] = hi; Gqlo[di] = lo; }
    else            { Gkhi[di] = hi; Gklo[di] = lo; }
  } else if (which == 2) {
    const int s = tid;
    const int top = s >> 6, mid = (s >> 4) & 3, low = s & 15;
    const int c = top >> 1, hh = top & 1;
    const int vkg = c * 4 + mid, vd = hh * 16 + low;
    const int n = hn & 1;
    const float* src = Vh + ((size_t)hn * TSEQ + tile * 64 + vkg * 8) * DHEAD + vd;
    const float* kmp = kmask + (size_t)n * TSEQ + tile * 64 + vkg * 8;
    half8 v8;
    #pragma unroll
    for (int j = 0; j < 8; ++j) v8[j] = (_Float16)(src[j * DHEAD] * kmp[j]);
    Gv[((size_t)hn * 32 + tile) * 256 + s] = v8;
  } else {
    if (hn >= NB || tid >= 128) return;
    const int n = hn;
    const int c = tid >> 6, lane = tid & 63;
    const int quad = lane >> 4, l15 = lane & 15;
    half8 am;
    #pragma unroll
    for (int j = 0; j < 8; ++j)
      am[j] = (l15 == 0) ? (_Float16)kmask[(size_t)n * TSEQ + tile * 64 + c * 32 + quad * 8 + j]
                         : (_Float16)0.0f;
    AmaskF[(((size_t)n * 32 + tile) * 2 + c) * 64 + lane] = am;
  }
}

// ---------------- MFMA flash attention, transposed-S, key-split x4 ----------------
// S^T = K·Q^T (rows=keys, cols=q): per-lane one q column -> scalar (m, alpha),
// in-thread key max + 2 shfl stages. PV as O^T = V^T·P (Gv frags already A-layout).
// l via mask-row A-frag MFMA (exact mask semantics; V also kmask-zeroed).
__global__ __launch_bounds__(256) void attn_kernel(
    const half8* __restrict__ Gqhi, const half8* __restrict__ Gqlo,
    const half8* __restrict__ Gkhi, const half8* __restrict__ Gklo,
    const half8* __restrict__ Gv, const half8* __restrict__ AmaskF,
    float* __restrict__ Op, float* __restrict__ Mp, float* __restrict__ Lp) {
  __shared__ __align__(16) half8 Vf[2][256];            // 8 KB double-buffered
  __shared__ __align__(16) _Float16 Pbuf[4][16][72];    // [wave][q][key], stride 144B

  const int tid = threadIdx.x;
  const int w = tid >> 6, lane = tid & 63;
  const int l15 = lane & 15, quad = lane >> 4;

  const int b = blockIdx.x;
  const int g    = ((b & 7) << 1) | ((b >> 3) & 1);   // hn, XCD-pinned
  const int qt   = (b >> 4) & 31;
  const int sblk = b >> 9;                            // 0..3
  const int n = g & 1;

  const size_t fbase = (size_t)g * 32 * 256;
  const int tile0 = sblk * TILES_PER;

  // Q fragment (B-operand): col q = w*16 + l15, k(d) = quad*8..+8
  half8 qhi = Gqhi[fbase + (size_t)qt * 256 + w * 64 + lane];
  half8 qlo = Gqlo[fbase + (size_t)qt * 256 + w * 64 + lane];

  float m_q = -1.0e30f;
  f32x4 O0, O1, Ol;
  O0 = (f32x4){0.f, 0.f, 0.f, 0.f};
  O1 = (f32x4){0.f, 0.f, 0.f, 0.f};
  Ol = (f32x4){0.f, 0.f, 0.f, 0.f};

  Vf[0][tid] = Gv[fbase + (size_t)tile0 * 256 + tid];

  for (int tt = 0; tt < TILES_PER; ++tt) {
    const int tile = tile0 + tt;
    half8 vnext;
    if (tt < TILES_PER - 1)
      vnext = Gv[fbase + (size_t)(tile + 1) * 256 + tid];
    __syncthreads();
    if (tt < TILES_PER - 1)
      Vf[(tt + 1) & 1][tid] = vnext;

    // mask-row fragments for this tile (VMEM, L2-hot)
    half8 am0 = AmaskF[(((size_t)n * 32 + tile) * 2 + 0) * 64 + lane];
    half8 am1 = AmaskF[(((size_t)n * 32 + tile) * 2 + 1) * 64 + lane];

    // S^T = K Q^T (split-fp16): rows = keys f*16+quad*4+r, col = q = l15
    const half8* kh = Gkhi + fbase + (size_t)tile * 256;
    const half8* kl = Gklo + fbase + (size_t)tile * 256;
    f32x4 S[4];
    #pragma unroll
    for (int f = 0; f < 4; ++f) {
      half8 KH = kh[f * 64 + lane];
      half8 KL = kl[f * 64 + lane];
      f32x4 a = (f32x4){0.f, 0.f, 0.f, 0.f};
      a = mfma16(KL, qhi, a);
      a = mfma16(KH, qlo, a);
      a = mfma16(KH, qhi, a);
      S[f] = a;
    }

    // column (per-q) max: 16 in-thread values + cross-quad shuffle
    float mx = S[0][0];
    #pragma unroll
    for (int f = 0; f < 4; ++f)
      #pragma unroll
      for (int r = 0; r < 4; ++r) mx = fmaxf(mx, S[f][r]);
    mx = fmaxf(mx, __shfl_xor(mx, 16));
    mx = fmaxf(mx, __shfl_xor(mx, 32));

    float mnew = fmaxf(m_q, mx);
    float alpha = exp2fast(m_q - mnew);
    m_q = mnew;

    // P = exp2(S - m), pack pairs along keys -> Pbuf[q][key]
    #pragma unroll
    for (int f = 0; f < 4; ++f) {
      float p0 = exp2fast(S[f][0] - m_q);
      float p1 = exp2fast(S[f][1] - m_q);
      float p2 = exp2fast(S[f][2] - m_q);
      float p3 = exp2fast(S[f][3] - m_q);
      half2t a01 = pkrtz(p0, p1);
      half2t a23 = pkrtz(p2, p3);
      *(half2t*)&Pbuf[w][l15][f * 16 + quad * 4]     = a01;
      *(half2t*)&Pbuf[w][l15][f * 16 + quad * 4 + 2] = a23;
    }
    #pragma unroll
    for (int r = 0; r < 4; ++r) { O0[r] *= alpha; O1[r] *= alpha; }
    Ol[0] *= alpha;
    // in-wave LDS RAW: drain DS queue before reading P as B-fragments
    asm volatile("s_waitcnt lgkmcnt(0)" ::: "memory");

    const half8* vbuf = (const half8*)Vf[tt & 1];
    #pragma unroll
    for (int c = 0; c < 2; ++c) {
      half8 pb = *(const half8*)&Pbuf[w][l15][c * 32 + quad * 8];
      O0 = mfma16(vbuf[(c * 2 + 0) * 64 + lane], pb, O0);
      O1 = mfma16(vbuf[(c * 2 + 1) * 64 + lane], pb, O1);
      Ol = mfma16(c == 0 ? am0 : am1, pb, Ol);
    }
  }

  // epilogue: O^T C-layout -> Op[q][d] with dwordx4 stores
  {
    int q = qt * 64 + w * 16 + l15;
    size_t idx = ((size_t)(sblk * 16 + g) * TSEQ + q) * DHEAD;
    *(f32x4*)&Op[idx + quad * 4]      = O0;
    *(f32x4*)&Op[idx + 16 + quad * 4] = O1;
    if (quad == 0) {
      Mp[(size_t)(sblk * 16 + g) * TSEQ + q] = m_q;
      Lp[(size_t)(sblk * 16 + g) * TSEQ + q] = Ol[0];
    }
  }
}

// ---------------- fused 4-way combine + layernorm + weight ----------------
__global__ __launch_bounds__(256) void ln_kernel(
    const float* __restrict__ Op, const float* __restrict__ Mp, const float* __restrict__ Lp,
    const float* __restrict__ gamma, const float* __restrict__ beta,
    const float* __restrict__ qmask,
    float* __restrict__ out, float* __restrict__ wout) {
  const int wid = threadIdx.x >> 6, lane = threadIdx.x & 63;
  const int row = blockIdx.x * 4 + wid;
  const int n = row >> 11, q = row & (TSEQ - 1);
  const int hh = lane >> 3;
  const int hn = hh * NB + n;
  const int dbase = (lane & 7) * 4;

  float4 P[SPLIT];
  float m[SPLIT], l[SPLIT];
  #pragma unroll
  for (int i = 0; i < SPLIT; ++i) {
    size_t si = (size_t)(i * 16 + hn) * TSEQ + q;
    P[i] = *(const float4*)(Op + si * DHEAD + dbase);
    m[i] = Mp[si];
    l[i] = Lp[si];
  }
  float mm = fmaxf(fmaxf(m[0], m[1]), fmaxf(m[2], m[3]));
  float denom = 0.f;
  float a[SPLIT];
  #pragma unroll
  for (int i = 0; i < SPLIT; ++i) { a[i] = exp2fast(m[i] - mm); denom += l[i] * a[i]; }
  float qm = qmask[row];
  float inv = qm / denom;

  float4 x = make_float4(0.f, 0.f, 0.f, 0.f);
  #pragma unroll
  for (int i = 0; i < SPLIT; ++i) {
    x.x += P[i].x * a[i]; x.y += P[i].y * a[i];
    x.z += P[i].z * a[i]; x.w += P[i].w * a[i];
  }
  x.x *= inv; x.y *= inv; x.z *= inv; x.w *= inv;

  float s = x.x + x.y + x.z + x.w;
  #pragma unroll
  for (int off = 32; off > 0; off >>= 1) s += __shfl_xor(s, off);
  float mu = s * (1.0f / H_DIM);
  float dx0 = x.x - mu, dx1 = x.y - mu, dx2 = x.z - mu, dx3 = x.w - mu;
  float sq = dx0 * dx0 + dx1 * dx1 + dx2 * dx2 + dx3 * dx3;
  #pragma unroll
  for (int off = 32; off > 0; off >>= 1) sq += __shfl_xor(sq, off);
  float rstd = rsqrtf(sq * (1.0f / H_DIM) + LN_EPS);
  float4 g = *(const float4*)(gamma + lane * 4);
  float4 bb = *(const float4*)(beta + lane * 4);
  float4 y;
  y.x = dx0 * rstd * g.x + bb.x;
  y.y = dx1 * rstd * g.y + bb.y;
  y.z = dx2 * rstd * g.z + bb.z;
  y.w = dx3 * rstd * g.w + bb.w;
  *(float4*)(out + (size_t)row * H_DIM + lane * 4) = y;
  if (lane == 0) wout[row] = qm * (1.0f / TSEQ);
}

extern "C" void kernel_launch(void* const* d_in, const int* in_sizes, int n_in,
                              void* d_out, int out_size, void* d_ws, size_t ws_size,
                              hipStream_t stream) {
  const float* Q  = (const float*)d_in[0];
  const float* K  = (const float*)d_in[1];
  const float* V  = (const float*)d_in[2];
  const float* Wq = (const float*)d_in[3];
  const float* bq = (const float*)d_in[4];
  const float* Wk = (const float*)d_in[5];
  const float* bk = (const float*)d_in[6];
  const float* Wv = (const float*)d_in[7];
  const float* bv = (const float*)d_in[8];
  const float* gamma = (const float*)d_in[9];
  const float* beta  = (const float*)d_in[10];

  float* ws = (float*)d_ws;
  const size_t perHN = (size_t)16 * TSEQ * DHEAD;    // 1,048,576 floats
  // fp32 QKV (proj->repack) and Opart (attn->ln) alias the same region.
  float* Qh = ws;
  float* Kh = Qh + perHN;
  float* Vh = Kh + perHN;
  float* Opart = ws;                                  // [SPLIT][16][TSEQ][DHEAD]
  float* tail = ws + 4 * perHN;
  const size_t NFRAG = (size_t)16 * 32 * 256;
  half8* Gqhi = (half8*)tail;
  half8* Gqlo = Gqhi + NFRAG;
  half8* Gkhi = Gqlo + NFRAG;
  half8* Gklo = Gkhi + NFRAG;
  half8* Gv   = Gklo + NFRAG;
  float* Mp = (float*)(Gv + NFRAG);                   // [SPLIT][16][TSEQ]
  float* Lp = Mp + SPLIT * 16 * TSEQ;
  float* qmask = Lp + SPLIT * 16 * TSEQ;
  float* kmask = qmask + NB * TSEQ;
  half8* WpkHi = (half8*)(kmask + NB * TSEQ);
  half8* WpkLo = WpkHi + 24576;
  half8* AmaskF = WpkLo + 24576;                      // [NB][32][2][64]

  float* out  = (float*)d_out;
  float* wout = out + (size_t)NB * TSEQ * H_DIM;

  hipLaunchKernelGGL(mask_kernel, dim3(2 * NB * TSEQ / 4), dim3(256), 0, stream,
                     Q, K, qmask, kmask);
  hipLaunchKernelGGL(prepack_kernel, dim3(96), dim3(256), 0, stream,
                     Wq, Wk, Wv, WpkHi, WpkLo);
  hipLaunchKernelGGL(proj_kernel, dim3(H_DIM / 64, NB * TSEQ / 64, 3), dim3(256), 0, stream,
                     Q, K, V, bq, bk, bv, WpkHi, WpkLo, Qh, Kh, Vh);
  hipLaunchKernelGGL(repack_kernel, dim3(32, 16, 4), dim3(256), 0, stream,
                     Qh, Kh, Vh, kmask, Gqhi, Gqlo, Gkhi, Gklo, Gv, AmaskF);
  hipLaunchKernelGGL(attn_kernel, dim3(16 * 32 * SPLIT), dim3(256), 0, stream,
                     Gqhi, Gqlo, Gkhi, Gklo, Gv, AmaskF, Opart, Mp, Lp);
  hipLaunchKernelGGL(ln_kernel, dim3(NB * TSEQ / 4), dim3(256), 0, stream,
                     Opart, Mp, Lp, gamma, beta, qmask, out, wout);
}

// Round 8
// 143.280 us; speedup vs baseline: 2.9230x; 1.0035x over previous
//
#include <hip/hip_runtime.h>
#include <math.h>

// Problem constants (fixed by reference)
#define H_DIM 256
#define NHEAD 8
#define DHEAD 32
#define NB 2
#define TSEQ 2048
#define LN_EPS 1e-5f

// softmax in exp2 domain: logit2 = s * (100/sqrt(32)) * log2(e).
// QK2_SCALE is folded into the packed Q fragments (repack_kernel).
#define QK2_SCALE 25.503486f
#define SPLIT 4                         // key-split factor
#define TILES_PER (TSEQ / 64 / SPLIT)   // 8 k-tiles per block

typedef _Float16 half8 __attribute__((ext_vector_type(8)));
typedef _Float16 half2t __attribute__((ext_vector_type(2)));
typedef float f32x4 __attribute__((ext_vector_type(4)));

__device__ __forceinline__ f32x4 mfma16(half8 a, half8 b, f32x4 c) {
  return __builtin_amdgcn_mfma_f32_16x16x32_f16(a, b, c, 0, 0, 0);
}
__device__ __forceinline__ float exp2fast(float x) {
  return __builtin_amdgcn_exp2f(x);
}
__device__ __forceinline__ half2t pkrtz(float a, float b) {
  return __builtin_bit_cast(half2t, __builtin_amdgcn_cvt_pkrtz(a, b));
}

// ---------------- masks: sign(sum|x|) per row ----------------
__global__ __launch_bounds__(256) void mask_kernel(
    const float* __restrict__ Q, const float* __restrict__ K,
    float* __restrict__ qmask, float* __restrict__ kmask) {
  const int wid = threadIdx.x >> 6, lane = threadIdx.x & 63;
  int row = blockIdx.x * 4 + wid;
  const int total_q = NB * TSEQ;
  const float* src;
  float* dst;
  if (row < total_q) { src = Q + (size_t)row * H_DIM; dst = qmask + row; }
  else               { src = K + (size_t)(row - total_q) * H_DIM; dst = kmask + (row - total_q); }
  float4 v = *(const float4*)(src + lane * 4);
  float s = fabsf(v.x) + fabsf(v.y) + fabsf(v.z) + fabsf(v.w);
  #pragma unroll
  for (int off = 32; off > 0; off >>= 1) s += __shfl_xor(s, off);
  if (lane == 0) *dst = (s != 0.0f) ? 1.0f : 0.0f;
}

// ---------------- W pre-pack: fp32 W -> hi/lo f16 B-fragment layout ----------------
__global__ __launch_bounds__(256) void prepack_kernel(
    const float* __restrict__ Wq, const float* __restrict__ Wk, const float* __restrict__ Wv,
    half8* __restrict__ WpkHi, half8* __restrict__ WpkLo) {
  int slot = blockIdx.x * 256 + threadIdx.x;
  int lane = slot & 63;
  int fg = (slot >> 6) & 15;
  int s  = (slot >> 10) & 7;
  int which = slot >> 13;
  const float* W = which == 0 ? Wq : which == 1 ? Wk : Wv;
  int j  = fg * 16 + (lane & 15);
  int kb = s * 32 + (lane >> 4) * 8;
  half8 hi, lo;
  #pragma unroll
  for (int jj = 0; jj < 8; ++jj) {
    float x = W[(size_t)(kb + jj) * H_DIM + j];
    _Float16 h = (_Float16)x;
    hi[jj] = h;
    lo[jj] = (_Float16)(x - (float)h);
  }
  WpkHi[slot] = hi;
  WpkLo[slot] = lo;
}

// ---------------- projection: relu(X @ W + b) via split-fp16 MFMA ----------------
__global__ __launch_bounds__(256) void proj_kernel(
    const float* __restrict__ Q, const float* __restrict__ K, const float* __restrict__ V,
    const float* __restrict__ bq, const float* __restrict__ bk, const float* __restrict__ bv,
    const half8* __restrict__ WpkHi, const half8* __restrict__ WpkLo,
    float* __restrict__ Qh, float* __restrict__ Kh, float* __restrict__ Vh) {
  const int which = blockIdx.z;
  const float* X    = which == 0 ? Q  : which == 1 ? K  : V;
  const float* bias = which == 0 ? bq : which == 1 ? bk : bv;
  float* dst        = which == 0 ? Qh : which == 1 ? Kh : Vh;

  const int tid = threadIdx.x;
  const int w = tid >> 6, lane = tid & 63;
  const int l15 = lane & 15, quad = lane >> 4;
  const int mbase = blockIdx.y * 64;
  const int nfg   = blockIdx.x * 4;

  half8 ahi[8], alo[8];
  {
    const float* xrow = X + (size_t)(mbase + w * 16 + l15) * H_DIM + quad * 8;
    #pragma unroll
    for (int s = 0; s < 8; ++s) {
      float4 a0 = *(const float4*)(xrow + s * 32);
      float4 a1 = *(const float4*)(xrow + s * 32 + 4);
      float xs[8] = {a0.x, a0.y, a0.z, a0.w, a1.x, a1.y, a1.z, a1.w};
      #pragma unroll
      for (int i = 0; i < 8; ++i) {
        _Float16 h = (_Float16)xs[i];
        ahi[s][i] = h;
        alo[s][i] = (_Float16)(xs[i] - (float)h);
      }
    }
  }

  f32x4 acc[4];
  #pragma unroll
  for (int f = 0; f < 4; ++f) acc[f] = (f32x4){0.f, 0.f, 0.f, 0.f};

  #pragma unroll
  for (int s = 0; s < 8; ++s) {
    const half8* ph = WpkHi + (((size_t)which * 8 + s) * 16 + nfg) * 64 + lane;
    const half8* pl = WpkLo + (((size_t)which * 8 + s) * 16 + nfg) * 64 + lane;
    #pragma unroll
    for (int f = 0; f < 4; ++f) {
      half8 BH = ph[f * 64];
      half8 BL = pl[f * 64];
      acc[f] = mfma16(ahi[s], BH, acc[f]);
      acc[f] = mfma16(ahi[s], BL, acc[f]);
      acc[f] = mfma16(alo[s], BH, acc[f]);
    }
  }

  #pragma unroll
  for (int f = 0; f < 4; ++f) {
    int j = blockIdx.x * 64 + f * 16 + l15;
    float bj = bias[j];
    int hh = j >> 5, dd = j & 31;
    #pragma unroll
    for (int r = 0; r < 4; ++r) {
      int m = mbase + w * 16 + quad * 4 + r;
      int n = m >> 11, t = m & (TSEQ - 1);
      float val = fmaxf(acc[f][r] + bj, 0.0f);
      if (which == 2 && t == TSEQ - 1) val = 0.0f;
      dst[(((size_t)hh * NB + n) * TSEQ + t) * DHEAD + dd] = val;
    }
  }
}

// ---------------- repack: fp32 head-split QKV -> MFMA fragment arrays ----------------
// Q/K frags: slot f*64 + quad*16 + l15 holds rows[tile*64 + f*16 + l15], d = quad*8..+8
// (Q pre-scaled by QK2_SCALE). V: transposed frags (8 keys of one d-col), kmask-zeroed.
// z==3: AmaskF[n][tile][c][lane] = mask-row A-fragment (row0 = kmask as f16).
__global__ __launch_bounds__(256) void repack_kernel(
    const float* __restrict__ Qh, const float* __restrict__ Kh, const float* __restrict__ Vh,
    const float* __restrict__ kmask,
    half8* __restrict__ Gqhi, half8* __restrict__ Gqlo,
    half8* __restrict__ Gkhi, half8* __restrict__ Gklo, half8* __restrict__ Gv,
    half8* __restrict__ AmaskF) {
  const int tile = blockIdx.x;      // 0..31
  const int hn   = blockIdx.y;      // 0..15 (= h*NB+n)
  const int which = blockIdx.z;     // 0:Q 1:K 2:V 3:AmaskF
  const int tid = threadIdx.x;
  if (which < 2) {
    const int w = tid >> 6, lane = tid & 63;
    const int f = w, krlo = lane & 15, kdc = lane >> 4;
    const float* src = (which == 0 ? Qh : Kh) +
        ((size_t)hn * TSEQ + tile * 64 + f * 16 + krlo) * DHEAD + kdc * 8;
    float4 a0 = *(const float4*)src;
    float4 a1 = *(const float4*)(src + 4);
    float xs[8] = {a0.x, a0.y, a0.z, a0.w, a1.x, a1.y, a1.z, a1.w};
    const float sc = which == 0 ? QK2_SCALE : 1.0f;
    half8 hi, lo;
    #pragma unroll
    for (int i = 0; i < 8; ++i) {
      float x = xs[i] * sc;
      _Float16 h = (_Float16)x;
      hi[i] = h;
      lo[i] = (_Float16)(x - (float)h);
    }
    size_t di = ((size_t)hn * 32 + tile) * 256 + f * 64 + kdc * 16 + krlo;
    if (which == 0) { Gqhi[di] = hi; Gqlo[di] = lo; }
    else            { Gkhi[di] = hi; Gklo[di] = lo; }
  } else if (which == 2) {
    const int s = tid;
    const int top = s >> 6, mid = (s >> 4) & 3, low = s & 15;
    const int c = top >> 1, hh = top & 1;
    const int vkg = c * 4 + mid, vd = hh * 16 + low;
    const int n = hn & 1;
    const float* src = Vh + ((size_t)hn * TSEQ + tile * 64 + vkg * 8) * DHEAD + vd;
    const float* kmp = kmask + (size_t)n * TSEQ + tile * 64 + vkg * 8;
    half8 v8;
    #pragma unroll
    for (int j = 0; j < 8; ++j) v8[j] = (_Float16)(src[j * DHEAD] * kmp[j]);
    Gv[((size_t)hn * 32 + tile) * 256 + s] = v8;
  } else {
    if (hn >= NB || tid >= 128) return;
    const int n = hn;
    const int c = tid >> 6, lane = tid & 63;
    const int quad = lane >> 4, l15 = lane & 15;
    half8 am;
    #pragma unroll
    for (int j = 0; j < 8; ++j)
      am[j] = (l15 == 0) ? (_Float16)kmask[(size_t)n * TSEQ + tile * 64 + c * 32 + quad * 8 + j]
                         : (_Float16)0.0f;
    AmaskF[(((size_t)n * 32 + tile) * 2 + c) * 64 + lane] = am;
  }
}

// ---------------- MFMA flash attention, transposed-S, key-split x4 ----------------
// S^T = K·Q^T (rows=keys, cols=q); K fragments software-pipelined global->reg
// (prefetch tile tt+1 during tile tt); full-unrolled 8-tile loop; V double-buffered
// in LDS; l via mask-row A-frag MFMA.
__global__ __launch_bounds__(256) void attn_kernel(
    const half8* __restrict__ Gqhi, const half8* __restrict__ Gqlo,
    const half8* __restrict__ Gkhi, const half8* __restrict__ Gklo,
    const half8* __restrict__ Gv, const half8* __restrict__ AmaskF,
    float* __restrict__ Op, float* __restrict__ Mp, float* __restrict__ Lp) {
  __shared__ __align__(16) half8 Vf[2][256];            // 8 KB double-buffered
  __shared__ __align__(16) _Float16 Pbuf[4][16][72];    // [wave][q][key], stride 144B

  const int tid = threadIdx.x;
  const int w = tid >> 6, lane = tid & 63;
  const int l15 = lane & 15, quad = lane >> 4;

  const int b = blockIdx.x;
  const int g    = ((b & 7) << 1) | ((b >> 3) & 1);   // hn, XCD-pinned
  const int qt   = (b >> 4) & 31;
  const int sblk = b >> 9;                            // 0..3
  const int n = g & 1;

  const size_t fbase = (size_t)g * 32 * 256;
  const int tile0 = sblk * TILES_PER;

  // Q fragment (B-operand): col q = w*16 + l15, k(d) = quad*8..+8
  half8 qhi = Gqhi[fbase + (size_t)qt * 256 + w * 64 + lane];
  half8 qlo = Gqlo[fbase + (size_t)qt * 256 + w * 64 + lane];

  float m_q = -1.0e30f;
  f32x4 O0, O1, Ol;
  O0 = (f32x4){0.f, 0.f, 0.f, 0.f};
  O1 = (f32x4){0.f, 0.f, 0.f, 0.f};
  Ol = (f32x4){0.f, 0.f, 0.f, 0.f};

  const half8* kh  = Gkhi + fbase + (size_t)tile0 * 256 + lane;
  const half8* kl  = Gklo + fbase + (size_t)tile0 * 256 + lane;
  const half8* gv  = Gv   + fbase + (size_t)tile0 * 256 + tid;
  const half8* amp = AmaskF + (((size_t)n * 32 + tile0) * 2) * 64 + lane;

  // preload tile 0 K fragments + V tile 0
  half8 KH[4], KL[4];
  #pragma unroll
  for (int f = 0; f < 4; ++f) { KH[f] = kh[f * 64]; KL[f] = kl[f * 64]; }
  Vf[0][tid] = gv[0];

  #pragma unroll
  for (int tt = 0; tt < TILES_PER; ++tt) {
    // prefetch next tile's K frags + V + mask frags while computing this one
    half8 KHn[4], KLn[4], vnext;
    if (tt < TILES_PER - 1) {
      #pragma unroll
      for (int f = 0; f < 4; ++f) { KHn[f] = kh[256 + f * 64]; KLn[f] = kl[256 + f * 64]; }
      vnext = gv[256];
    }
    half8 am0 = amp[0];
    half8 am1 = amp[64];

    __syncthreads();     // Vf[tt&1] writes visible; all reads of Vf[(tt+1)&1] done
    if (tt < TILES_PER - 1)
      Vf[(tt + 1) & 1][tid] = vnext;

    // S^T = K Q^T (split-fp16): rows = keys f*16+quad*4+r, col = q = l15
    f32x4 S[4];
    #pragma unroll
    for (int f = 0; f < 4; ++f) {
      f32x4 a = (f32x4){0.f, 0.f, 0.f, 0.f};
      a = mfma16(KL[f], qhi, a);
      a = mfma16(KH[f], qlo, a);
      a = mfma16(KH[f], qhi, a);
      S[f] = a;
    }

    // column (per-q) max: balanced tree (max3-friendly) + 2 shuffle stages
    float t0 = fmaxf(fmaxf(S[0][0], S[0][1]), fmaxf(S[0][2], S[0][3]));
    float t1 = fmaxf(fmaxf(S[1][0], S[1][1]), fmaxf(S[1][2], S[1][3]));
    float t2 = fmaxf(fmaxf(S[2][0], S[2][1]), fmaxf(S[2][2], S[2][3]));
    float t3 = fmaxf(fmaxf(S[3][0], S[3][1]), fmaxf(S[3][2], S[3][3]));
    float mx = fmaxf(fmaxf(t0, t1), fmaxf(t2, t3));
    mx = fmaxf(mx, __shfl_xor(mx, 16));
    mx = fmaxf(mx, __shfl_xor(mx, 32));

    float mnew = fmaxf(m_q, mx);
    float alpha = exp2fast(m_q - mnew);
    m_q = mnew;

    // P = exp2(S - m), pack pairs along keys -> Pbuf[q][key]
    #pragma unroll
    for (int f = 0; f < 4; ++f) {
      float p0 = exp2fast(S[f][0] - m_q);
      float p1 = exp2fast(S[f][1] - m_q);
      float p2 = exp2fast(S[f][2] - m_q);
      float p3 = exp2fast(S[f][3] - m_q);
      half2t a01 = pkrtz(p0, p1);
      half2t a23 = pkrtz(p2, p3);
      *(half2t*)&Pbuf[w][l15][f * 16 + quad * 4]     = a01;
      *(half2t*)&Pbuf[w][l15][f * 16 + quad * 4 + 2] = a23;
    }
    #pragma unroll
    for (int r = 0; r < 4; ++r) { O0[r] *= alpha; O1[r] *= alpha; }
    Ol[0] *= alpha;
    // in-wave LDS RAW: drain DS queue before reading P as B-fragments
    asm volatile("s_waitcnt lgkmcnt(0)" ::: "memory");

    const half8* vbuf = (const half8*)Vf[tt & 1];
    #pragma unroll
    for (int c = 0; c < 2; ++c) {
      half8 pb = *(const half8*)&Pbuf[w][l15][c * 32 + quad * 8];
      O0 = mfma16(vbuf[(c * 2 + 0) * 64 + lane], pb, O0);
      O1 = mfma16(vbuf[(c * 2 + 1) * 64 + lane], pb, O1);
      Ol = mfma16(c == 0 ? am0 : am1, pb, Ol);
    }

    // rotate prefetched registers (free under full unroll)
    #pragma unroll
    for (int f = 0; f < 4; ++f) { KH[f] = KHn[f]; KL[f] = KLn[f]; }
    kh += 256; kl += 256; gv += 256; amp += 128;
  }

  // epilogue: O^T C-layout -> Op[q][d] with dwordx4 stores
  {
    int q = qt * 64 + w * 16 + l15;
    size_t idx = ((size_t)(sblk * 16 + g) * TSEQ + q) * DHEAD;
    *(f32x4*)&Op[idx + quad * 4]      = O0;
    *(f32x4*)&Op[idx + 16 + quad * 4] = O1;
    if (quad == 0) {
      Mp[(size_t)(sblk * 16 + g) * TSEQ + q] = m_q;
      Lp[(size_t)(sblk * 16 + g) * TSEQ + q] = Ol[0];
    }
  }
}

// ---------------- fused 4-way combine + layernorm + weight ----------------
__global__ __launch_bounds__(256) void ln_kernel(
    const float* __restrict__ Op, const float* __restrict__ Mp, const float* __restrict__ Lp,
    const float* __restrict__ gamma, const float* __restrict__ beta,
    const float* __restrict__ qmask,
    float* __restrict__ out, float* __restrict__ wout) {
  const int wid = threadIdx.x >> 6, lane = threadIdx.x & 63;
  const int row = blockIdx.x * 4 + wid;
  const int n = row >> 11, q = row & (TSEQ - 1);
  const int hh = lane >> 3;
  const int hn = hh * NB + n;
  const int dbase = (lane & 7) * 4;

  float4 P[SPLIT];
  float m[SPLIT], l[SPLIT];
  #pragma unroll
  for (int i = 0; i < SPLIT; ++i) {
    size_t si = (size_t)(i * 16 + hn) * TSEQ + q;
    P[i] = *(const float4*)(Op + si * DHEAD + dbase);
    m[i] = Mp[si];
    l[i] = Lp[si];
  }
  float mm = fmaxf(fmaxf(m[0], m[1]), fmaxf(m[2], m[3]));
  float denom = 0.f;
  float a[SPLIT];
  #pragma unroll
  for (int i = 0; i < SPLIT; ++i) { a[i] = exp2fast(m[i] - mm); denom += l[i] * a[i]; }
  float qm = qmask[row];
  float inv = qm / denom;

  float4 x = make_float4(0.f, 0.f, 0.f, 0.f);
  #pragma unroll
  for (int i = 0; i < SPLIT; ++i) {
    x.x += P[i].x * a[i]; x.y += P[i].y * a[i];
    x.z += P[i].z * a[i]; x.w += P[i].w * a[i];
  }
  x.x *= inv; x.y *= inv; x.z *= inv; x.w *= inv;

  float s = x.x + x.y + x.z + x.w;
  #pragma unroll
  for (int off = 32; off > 0; off >>= 1) s += __shfl_xor(s, off);
  float mu = s * (1.0f / H_DIM);
  float dx0 = x.x - mu, dx1 = x.y - mu, dx2 = x.z - mu, dx3 = x.w - mu;
  float sq = dx0 * dx0 + dx1 * dx1 + dx2 * dx2 + dx3 * dx3;
  #pragma unroll
  for (int off = 32; off > 0; off >>= 1) sq += __shfl_xor(sq, off);
  float rstd = rsqrtf(sq * (1.0f / H_DIM) + LN_EPS);
  float4 g = *(const float4*)(gamma + lane * 4);
  float4 bb = *(const float4*)(beta + lane * 4);
  float4 y;
  y.x = dx0 * rstd * g.x + bb.x;
  y.y = dx1 * rstd * g.y + bb.y;
  y.z = dx2 * rstd * g.z + bb.z;
  y.w = dx3 * rstd * g.w + bb.w;
  *(float4*)(out + (size_t)row * H_DIM + lane * 4) = y;
  if (lane == 0) wout[row] = qm * (1.0f / TSEQ);
}

extern "C" void kernel_launch(void* const* d_in, const int* in_sizes, int n_in,
                              void* d_out, int out_size, void* d_ws, size_t ws_size,
                              hipStream_t stream) {
  const float* Q  = (const float*)d_in[0];
  const float* K  = (const float*)d_in[1];
  const float* V  = (const float*)d_in[2];
  const float* Wq = (const float*)d_in[3];
  const float* bq = (const float*)d_in[4];
  const float* Wk = (const float*)d_in[5];
  const float* bk = (const float*)d_in[6];
  const float* Wv = (const float*)d_in[7];
  const float* bv = (const float*)d_in[8];
  const float* gamma = (const float*)d_in[9];
  const float* beta  = (const float*)d_in[10];

  float* ws = (float*)d_ws;
  const size_t perHN = (size_t)16 * TSEQ * DHEAD;    // 1,048,576 floats
  // fp32 QKV (proj->repack) and Opart (attn->ln) alias the same region.
  float* Qh = ws;
  float* Kh = Qh + perHN;
  float* Vh = Kh + perHN;
  float* Opart = ws;                                  // [SPLIT][16][TSEQ][DHEAD]
  float* tail = ws + 4 * perHN;
  const size_t NFRAG = (size_t)16 * 32 * 256;
  half8* Gqhi = (half8*)tail;
  half8* Gqlo = Gqhi + NFRAG;
  half8* Gkhi = Gqlo + NFRAG;
  half8* Gklo = Gkhi + NFRAG;
  half8* Gv   = Gklo + NFRAG;
  float* Mp = (float*)(Gv + NFRAG);                   // [SPLIT][16][TSEQ]
  float* Lp = Mp + SPLIT * 16 * TSEQ;
  float* qmask = Lp + SPLIT * 16 * TSEQ;
  float* kmask = qmask + NB * TSEQ;
  half8* WpkHi = (half8*)(kmask + NB * TSEQ);
  half8* WpkLo = WpkHi + 24576;
  half8* AmaskF = WpkLo + 24576;                      // [NB][32][2][64]

  float* out  = (float*)d_out;
  float* wout = out + (size_t)NB * TSEQ * H_DIM;

  hipLaunchKernelGGL(mask_kernel, dim3(2 * NB * TSEQ / 4), dim3(256), 0, stream,
                     Q, K, qmask, kmask);
  hipLaunchKernelGGL(prepack_kernel, dim3(96), dim3(256), 0, stream,
                     Wq, Wk, Wv, WpkHi, WpkLo);
  hipLaunchKernelGGL(proj_kernel, dim3(H_DIM / 64, NB * TSEQ / 64, 3), dim3(256), 0, stream,
                     Q, K, V, bq, bk, bv, WpkHi, WpkLo, Qh, Kh, Vh);
  hipLaunchKernelGGL(repack_kernel, dim3(32, 16, 4), dim3(256), 0, stream,
                     Qh, Kh, Vh, kmask, Gqhi, Gqlo, Gkhi, Gklo, Gv, AmaskF);
  hipLaunchKernelGGL(attn_kernel, dim3(16 * 32 * SPLIT), dim3(256), 0, stream,
                     Gqhi, Gqlo, Gkhi, Gklo, Gv, AmaskF, Opart, Mp, Lp);
  hipLaunchKernelGGL(ln_kernel, dim3(NB * TSEQ / 4), dim3(256), 0, stream,
                     Opart, Mp, Lp, gamma, beta, qmask, out, wout);
}

// Round 9
// 131.774 us; speedup vs baseline: 3.1782x; 1.0873x over previous
//
#include <hip/hip_runtime.h>
#include <math.h>

// Problem constants (fixed by reference)
#define H_DIM 256
#define NHEAD 8
#define DHEAD 32
#define NB 2
#define TSEQ 2048
#define LN_EPS 1e-5f

// softmax in exp2 domain: logit2 = s * (100/sqrt(32)) * log2(e).
// QK2_SCALE is folded into the packed Q fragments (proj frag-gen).
#define QK2_SCALE 25.503486f
#define SPLIT 4                         // key-split factor
#define TILES_PER (TSEQ / 64 / SPLIT)   // 8 k-tiles per block

typedef _Float16 half8 __attribute__((ext_vector_type(8)));
typedef _Float16 half4t __attribute__((ext_vector_type(4)));
typedef _Float16 half2t __attribute__((ext_vector_type(2)));
typedef float f32x4 __attribute__((ext_vector_type(4)));

__device__ __forceinline__ f32x4 mfma16(half8 a, half8 b, f32x4 c) {
  return __builtin_amdgcn_mfma_f32_16x16x32_f16(a, b, c, 0, 0, 0);
}
__device__ __forceinline__ float exp2fast(float x) {
  return __builtin_amdgcn_exp2f(x);
}
__device__ __forceinline__ half2t pkrtz(float a, float b) {
  return __builtin_bit_cast(half2t, __builtin_amdgcn_cvt_pkrtz(a, b));
}

// ---------------- masks: sign(sum|x|) per row ----------------
__global__ __launch_bounds__(256) void mask_kernel(
    const float* __restrict__ Q, const float* __restrict__ K,
    float* __restrict__ qmask, float* __restrict__ kmask) {
  const int wid = threadIdx.x >> 6, lane = threadIdx.x & 63;
  int row = blockIdx.x * 4 + wid;
  const int total_q = NB * TSEQ;
  const float* src;
  float* dst;
  if (row < total_q) { src = Q + (size_t)row * H_DIM; dst = qmask + row; }
  else               { src = K + (size_t)(row - total_q) * H_DIM; dst = kmask + (row - total_q); }
  float4 v = *(const float4*)(src + lane * 4);
  float s = fabsf(v.x) + fabsf(v.y) + fabsf(v.z) + fabsf(v.w);
  #pragma unroll
  for (int off = 32; off > 0; off >>= 1) s += __shfl_xor(s, off);
  if (lane == 0) *dst = (s != 0.0f) ? 1.0f : 0.0f;
}

// ---------------- W pre-pack (+ AmaskF build, blocks >= 96) ----------------
// W: fp32 -> hi/lo f16 B-fragment layout. AmaskF[n][tile][c][lane]: mask-row
// A-fragment (row0 = kmask as f16). Must launch AFTER mask_kernel.
__global__ __launch_bounds__(256) void prepack_kernel(
    const float* __restrict__ Wq, const float* __restrict__ Wk, const float* __restrict__ Wv,
    const float* __restrict__ kmask,
    half8* __restrict__ WpkHi, half8* __restrict__ WpkLo, half8* __restrict__ AmaskF) {
  if (blockIdx.x >= 96) {
    int slot2 = (blockIdx.x - 96) * 256 + threadIdx.x;   // 0..8191
    int n = slot2 >> 12;
    int rem = slot2 & 4095;
    int tile = rem >> 7;
    int c = (rem >> 6) & 1;
    int lane = rem & 63;
    int quad = lane >> 4, l15 = lane & 15;
    half8 am;
    #pragma unroll
    for (int j = 0; j < 8; ++j)
      am[j] = (l15 == 0) ? (_Float16)kmask[(size_t)n * TSEQ + tile * 64 + c * 32 + quad * 8 + j]
                         : (_Float16)0.0f;
    AmaskF[(((size_t)n * 32 + tile) * 2 + c) * 64 + lane] = am;
    return;
  }
  int slot = blockIdx.x * 256 + threadIdx.x;
  int lane = slot & 63;
  int fg = (slot >> 6) & 15;
  int s  = (slot >> 10) & 7;
  int which = slot >> 13;
  const float* W = which == 0 ? Wq : which == 1 ? Wk : Wv;
  int j  = fg * 16 + (lane & 15);
  int kb = s * 32 + (lane >> 4) * 8;
  half8 hi, lo;
  #pragma unroll
  for (int jj = 0; jj < 8; ++jj) {
    float x = W[(size_t)(kb + jj) * H_DIM + j];
    _Float16 h = (_Float16)x;
    hi[jj] = h;
    lo[jj] = (_Float16)(x - (float)h);
  }
  WpkHi[slot] = hi;
  WpkLo[slot] = lo;
}

// ---------------- fused projection + frag repack ----------------
// relu(X@W+b) via split-fp16 MFMA; result tile (64 t x 64 j = 2 heads) goes
// through LDS transpose and exits directly as MFMA fragment arrays:
//   Q/K: hi/lo split-f16 frags (Q pre-scaled by QK2_SCALE)
//   V:   transposed f16 frags, kmask- and t==2047-zeroed.
// No fp32 intermediate ever touches global memory.
__global__ __launch_bounds__(256) void proj_kernel(
    const float* __restrict__ Q, const float* __restrict__ K, const float* __restrict__ V,
    const float* __restrict__ bq, const float* __restrict__ bk, const float* __restrict__ bv,
    const half8* __restrict__ WpkHi, const half8* __restrict__ WpkLo,
    const float* __restrict__ kmask,
    half8* __restrict__ Gqhi, half8* __restrict__ Gqlo,
    half8* __restrict__ Gkhi, half8* __restrict__ Gklo, half8* __restrict__ Gv) {
  const int which = blockIdx.z;
  const float* X    = which == 0 ? Q  : which == 1 ? K  : V;
  const float* bias = which == 0 ? bq : which == 1 ? bk : bv;

  __shared__ __align__(16) float T[64 * 68];   // 17408 B, stride 68 words

  const int tid = threadIdx.x;
  const int w = tid >> 6, lane = tid & 63;
  const int l15 = lane & 15, quad = lane >> 4;
  const int mbase = blockIdx.y * 64;
  const int nfg   = blockIdx.x * 4;
  const int nn   = mbase >> 11;        // batch
  const int tile = blockIdx.y & 31;    // 64-row tile within batch

  half8 ahi[8], alo[8];
  {
    const float* xrow = X + (size_t)(mbase + w * 16 + l15) * H_DIM + quad * 8;
    #pragma unroll
    for (int s = 0; s < 8; ++s) {
      float4 a0 = *(const float4*)(xrow + s * 32);
      float4 a1 = *(const float4*)(xrow + s * 32 + 4);
      float xs[8] = {a0.x, a0.y, a0.z, a0.w, a1.x, a1.y, a1.z, a1.w};
      #pragma unroll
      for (int i = 0; i < 8; ++i) {
        _Float16 h = (_Float16)xs[i];
        ahi[s][i] = h;
        alo[s][i] = (_Float16)(xs[i] - (float)h);
      }
    }
  }

  f32x4 acc[4];
  #pragma unroll
  for (int f = 0; f < 4; ++f) acc[f] = (f32x4){0.f, 0.f, 0.f, 0.f};

  #pragma unroll
  for (int s = 0; s < 8; ++s) {
    const half8* ph = WpkHi + (((size_t)which * 8 + s) * 16 + nfg) * 64 + lane;
    const half8* pl = WpkLo + (((size_t)which * 8 + s) * 16 + nfg) * 64 + lane;
    #pragma unroll
    for (int f = 0; f < 4; ++f) {
      half8 BH = ph[f * 64];
      half8 BL = pl[f * 64];
      acc[f] = mfma16(ahi[s], BH, acc[f]);
      acc[f] = mfma16(ahi[s], BL, acc[f]);
      acc[f] = mfma16(alo[s], BH, acc[f]);
    }
  }

  // bias + relu (+ V last-key zero) -> LDS tile [t'][j]
  #pragma unroll
  for (int f = 0; f < 4; ++f) {
    float bj = bias[blockIdx.x * 64 + f * 16 + l15];
    #pragma unroll
    for (int r = 0; r < 4; ++r) {
      int row = w * 16 + quad * 4 + r;      // t' within tile
      float val = fmaxf(acc[f][r] + bj, 0.0f);
      if (which == 2 && ((mbase + row) & (TSEQ - 1)) == TSEQ - 1) val = 0.0f;
      T[row * 68 + f * 16 + l15] = val;
    }
  }
  __syncthreads();

  // fragment generation (2 heads per block: hs = 0,1 -> h = blockIdx.x*2+hs)
  if (which < 2) {
    const int fq = tid >> 6, lp = tid & 63;
    const int kdc = lp >> 4, krlo = lp & 15;
    const int row = fq * 16 + krlo;
    const float sc = (which == 0) ? QK2_SCALE : 1.0f;
    #pragma unroll
    for (int hs = 0; hs < 2; ++hs) {
      const float* p = &T[row * 68 + hs * 32 + kdc * 8];
      float4 a0 = *(const float4*)p;
      float4 a1 = *(const float4*)(p + 4);
      float xs[8] = {a0.x, a0.y, a0.z, a0.w, a1.x, a1.y, a1.z, a1.w};
      half8 hi, lo;
      #pragma unroll
      for (int i = 0; i < 8; ++i) {
        float x = xs[i] * sc;
        _Float16 h = (_Float16)x;
        hi[i] = h;
        lo[i] = (_Float16)(x - (float)h);
      }
      int hn = (blockIdx.x * 2 + hs) * NB + nn;
      size_t di = ((size_t)hn * 32 + tile) * 256 + tid;
      if (which == 0) { Gqhi[di] = hi; Gqlo[di] = lo; }
      else            { Gkhi[di] = hi; Gklo[di] = lo; }
    }
  } else {
    const int top = tid >> 6, mid = (tid >> 4) & 3, low = tid & 15;
    const int c = top >> 1, hh = top & 1;
    const int trow0 = (c * 4 + mid) * 8;
    float km[8];
    #pragma unroll
    for (int j = 0; j < 8; ++j)
      km[j] = kmask[(size_t)nn * TSEQ + tile * 64 + trow0 + j];
    #pragma unroll
    for (int hs = 0; hs < 2; ++hs) {
      const int col = hs * 32 + hh * 16 + low;
      half8 v8;
      #pragma unroll
      for (int j = 0; j < 8; ++j)
        v8[j] = (_Float16)(T[(trow0 + j) * 68 + col] * km[j]);
      int hn = (blockIdx.x * 2 + hs) * NB + nn;
      Gv[((size_t)hn * 32 + tile) * 256 + tid] = v8;
    }
  }
}

// ---------------- MFMA flash attention, transposed-S, key-split x4 ----------------
// S^T = K·Q^T (rows=keys, cols=q); K fragments global->reg (L2-hot, pipelined);
// V double-buffered in LDS; l via mask-row A-frag MFMA; f16 partial output.
__global__ __launch_bounds__(256) void attn_kernel(
    const half8* __restrict__ Gqhi, const half8* __restrict__ Gqlo,
    const half8* __restrict__ Gkhi, const half8* __restrict__ Gklo,
    const half8* __restrict__ Gv, const half8* __restrict__ AmaskF,
    _Float16* __restrict__ Opf, float* __restrict__ Mp, float* __restrict__ Lp) {
  __shared__ __align__(16) half8 Vf[2][256];            // 8 KB double-buffered
  __shared__ __align__(16) _Float16 Pbuf[4][16][72];    // [wave][q][key], stride 144B

  const int tid = threadIdx.x;
  const int w = tid >> 6, lane = tid & 63;
  const int l15 = lane & 15, quad = lane >> 4;

  const int b = blockIdx.x;
  const int g    = ((b & 7) << 1) | ((b >> 3) & 1);   // hn, XCD-pinned
  const int qt   = (b >> 4) & 31;
  const int sblk = b >> 9;                            // 0..3
  const int n = g & 1;

  const size_t fbase = (size_t)g * 32 * 256;
  const int tile0 = sblk * TILES_PER;

  // Q fragment (B-operand): col q = w*16 + l15, k(d) = quad*8..+8
  half8 qhi = Gqhi[fbase + (size_t)qt * 256 + w * 64 + lane];
  half8 qlo = Gqlo[fbase + (size_t)qt * 256 + w * 64 + lane];

  float m_q = -1.0e30f;
  f32x4 O0, O1, Ol;
  O0 = (f32x4){0.f, 0.f, 0.f, 0.f};
  O1 = (f32x4){0.f, 0.f, 0.f, 0.f};
  Ol = (f32x4){0.f, 0.f, 0.f, 0.f};

  const half8* kh  = Gkhi + fbase + (size_t)tile0 * 256 + lane;
  const half8* kl  = Gklo + fbase + (size_t)tile0 * 256 + lane;
  const half8* gv  = Gv   + fbase + (size_t)tile0 * 256 + tid;
  const half8* amp = AmaskF + (((size_t)n * 32 + tile0) * 2) * 64 + lane;

  half8 KH[4], KL[4];
  #pragma unroll
  for (int f = 0; f < 4; ++f) { KH[f] = kh[f * 64]; KL[f] = kl[f * 64]; }
  Vf[0][tid] = gv[0];

  #pragma unroll
  for (int tt = 0; tt < TILES_PER; ++tt) {
    half8 KHn[4], KLn[4], vnext;
    if (tt < TILES_PER - 1) {
      #pragma unroll
      for (int f = 0; f < 4; ++f) { KHn[f] = kh[256 + f * 64]; KLn[f] = kl[256 + f * 64]; }
      vnext = gv[256];
    }
    half8 am0 = amp[0];
    half8 am1 = amp[64];

    __syncthreads();
    if (tt < TILES_PER - 1)
      Vf[(tt + 1) & 1][tid] = vnext;

    // S^T = K Q^T (split-fp16): rows = keys f*16+quad*4+r, col = q = l15
    f32x4 S[4];
    #pragma unroll
    for (int f = 0; f < 4; ++f) {
      f32x4 a = (f32x4){0.f, 0.f, 0.f, 0.f};
      a = mfma16(KL[f], qhi, a);
      a = mfma16(KH[f], qlo, a);
      a = mfma16(KH[f], qhi, a);
      S[f] = a;
    }

    // per-q max: balanced tree + 2 shuffle stages
    float t0 = fmaxf(fmaxf(S[0][0], S[0][1]), fmaxf(S[0][2], S[0][3]));
    float t1 = fmaxf(fmaxf(S[1][0], S[1][1]), fmaxf(S[1][2], S[1][3]));
    float t2 = fmaxf(fmaxf(S[2][0], S[2][1]), fmaxf(S[2][2], S[2][3]));
    float t3 = fmaxf(fmaxf(S[3][0], S[3][1]), fmaxf(S[3][2], S[3][3]));
    float mx = fmaxf(fmaxf(t0, t1), fmaxf(t2, t3));
    mx = fmaxf(mx, __shfl_xor(mx, 16));
    mx = fmaxf(mx, __shfl_xor(mx, 32));

    float mnew = fmaxf(m_q, mx);
    float alpha = exp2fast(m_q - mnew);
    m_q = mnew;

    // P = exp2(S - m), pack pairs along keys -> Pbuf[q][key]
    #pragma unroll
    for (int f = 0; f < 4; ++f) {
      float p0 = exp2fast(S[f][0] - m_q);
      float p1 = exp2fast(S[f][1] - m_q);
      float p2 = exp2fast(S[f][2] - m_q);
      float p3 = exp2fast(S[f][3] - m_q);
      half2t a01 = pkrtz(p0, p1);
      half2t a23 = pkrtz(p2, p3);
      *(half2t*)&Pbuf[w][l15][f * 16 + quad * 4]     = a01;
      *(half2t*)&Pbuf[w][l15][f * 16 + quad * 4 + 2] = a23;
    }
    #pragma unroll
    for (int r = 0; r < 4; ++r) { O0[r] *= alpha; O1[r] *= alpha; }
    Ol[0] *= alpha;
    // in-wave LDS RAW: drain DS queue before reading P as B-fragments
    asm volatile("s_waitcnt lgkmcnt(0)" ::: "memory");

    const half8* vbuf = (const half8*)Vf[tt & 1];
    #pragma unroll
    for (int c = 0; c < 2; ++c) {
      half8 pb = *(const half8*)&Pbuf[w][l15][c * 32 + quad * 8];
      O0 = mfma16(vbuf[(c * 2 + 0) * 64 + lane], pb, O0);
      O1 = mfma16(vbuf[(c * 2 + 1) * 64 + lane], pb, O1);
      Ol = mfma16(c == 0 ? am0 : am1, pb, Ol);
    }

    #pragma unroll
    for (int f = 0; f < 4; ++f) { KH[f] = KHn[f]; KL[f] = KLn[f]; }
    kh += 256; kl += 256; gv += 256; amp += 128;
  }

  // epilogue: f16 partials (d = quad*4..+4 and +16), m/l from quad 0
  {
    int q = qt * 64 + w * 16 + l15;
    size_t idx = ((size_t)(sblk * 16 + g) * TSEQ + q) * DHEAD;
    half4t o0 = {(_Float16)O0[0], (_Float16)O0[1], (_Float16)O0[2], (_Float16)O0[3]};
    half4t o1 = {(_Float16)O1[0], (_Float16)O1[1], (_Float16)O1[2], (_Float16)O1[3]};
    *(half4t*)&Opf[idx + quad * 4]      = o0;
    *(half4t*)&Opf[idx + 16 + quad * 4] = o1;
    if (quad == 0) {
      Mp[(size_t)(sblk * 16 + g) * TSEQ + q] = m_q;
      Lp[(size_t)(sblk * 16 + g) * TSEQ + q] = Ol[0];
    }
  }
}

// ---------------- fused 4-way combine + layernorm + weight ----------------
__global__ __launch_bounds__(256) void ln_kernel(
    const _Float16* __restrict__ Opf, const float* __restrict__ Mp, const float* __restrict__ Lp,
    const float* __restrict__ gamma, const float* __restrict__ beta,
    const float* __restrict__ qmask,
    float* __restrict__ out, float* __restrict__ wout) {
  const int wid = threadIdx.x >> 6, lane = threadIdx.x & 63;
  const int row = blockIdx.x * 4 + wid;
  const int n = row >> 11, q = row & (TSEQ - 1);
  const int hh = lane >> 3;
  const int hn = hh * NB + n;
  const int dbase = (lane & 7) * 4;

  float m[SPLIT], l[SPLIT];
  half4t P[SPLIT];
  #pragma unroll
  for (int i = 0; i < SPLIT; ++i) {
    size_t si = (size_t)(i * 16 + hn) * TSEQ + q;
    P[i] = *(const half4t*)&Opf[si * DHEAD + dbase];
    m[i] = Mp[si];
    l[i] = Lp[si];
  }
  float mm = fmaxf(fmaxf(m[0], m[1]), fmaxf(m[2], m[3]));
  float denom = 0.f;
  float a[SPLIT];
  #pragma unroll
  for (int i = 0; i < SPLIT; ++i) { a[i] = exp2fast(m[i] - mm); denom += l[i] * a[i]; }
  float qm = qmask[row];
  float inv = qm / denom;

  float4 x = make_float4(0.f, 0.f, 0.f, 0.f);
  #pragma unroll
  for (int i = 0; i < SPLIT; ++i) {
    x.x += (float)P[i][0] * a[i]; x.y += (float)P[i][1] * a[i];
    x.z += (float)P[i][2] * a[i]; x.w += (float)P[i][3] * a[i];
  }
  x.x *= inv; x.y *= inv; x.z *= inv; x.w *= inv;

  float s = x.x + x.y + x.z + x.w;
  #pragma unroll
  for (int off = 32; off > 0; off >>= 1) s += __shfl_xor(s, off);
  float mu = s * (1.0f / H_DIM);
  float dx0 = x.x - mu, dx1 = x.y - mu, dx2 = x.z - mu, dx3 = x.w - mu;
  float sq = dx0 * dx0 + dx1 * dx1 + dx2 * dx2 + dx3 * dx3;
  #pragma unroll
  for (int off = 32; off > 0; off >>= 1) sq += __shfl_xor(sq, off);
  float rstd = rsqrtf(sq * (1.0f / H_DIM) + LN_EPS);
  float4 g = *(const float4*)(gamma + lane * 4);
  float4 bb = *(const float4*)(beta + lane * 4);
  float4 y;
  y.x = dx0 * rstd * g.x + bb.x;
  y.y = dx1 * rstd * g.y + bb.y;
  y.z = dx2 * rstd * g.z + bb.z;
  y.w = dx3 * rstd * g.w + bb.w;
  *(float4*)(out + (size_t)row * H_DIM + lane * 4) = y;
  if (lane == 0) wout[row] = qm * (1.0f / TSEQ);
}

extern "C" void kernel_launch(void* const* d_in, const int* in_sizes, int n_in,
                              void* d_out, int out_size, void* d_ws, size_t ws_size,
                              hipStream_t stream) {
  const float* Q  = (const float*)d_in[0];
  const float* K  = (const float*)d_in[1];
  const float* V  = (const float*)d_in[2];
  const float* Wq = (const float*)d_in[3];
  const float* bq = (const float*)d_in[4];
  const float* Wk = (const float*)d_in[5];
  const float* bk = (const float*)d_in[6];
  const float* Wv = (const float*)d_in[7];
  const float* bv = (const float*)d_in[8];
  const float* gamma = (const float*)d_in[9];
  const float* beta  = (const float*)d_in[10];

  char* ws = (char*)d_ws;
  const size_t NFRAG = (size_t)16 * 32 * 256;            // frags per array
  _Float16* Opf = (_Float16*)ws;                          // [SPLIT][16][TSEQ][32] f16 = 8 MB
  half8* Gqhi = (half8*)(ws + (size_t)SPLIT * 16 * TSEQ * DHEAD * 2);
  half8* Gqlo = Gqhi + NFRAG;
  half8* Gkhi = Gqlo + NFRAG;
  half8* Gklo = Gkhi + NFRAG;
  half8* Gv   = Gklo + NFRAG;
  float* Mp = (float*)(Gv + NFRAG);                       // [SPLIT][16][TSEQ]
  float* Lp = Mp + SPLIT * 16 * TSEQ;
  float* qmask = Lp + SPLIT * 16 * TSEQ;
  float* kmask = qmask + NB * TSEQ;
  half8* WpkHi = (half8*)(kmask + NB * TSEQ);
  half8* WpkLo = WpkHi + 24576;
  half8* AmaskF = WpkLo + 24576;                          // [NB][32][2][64]

  float* out  = (float*)d_out;
  float* wout = out + (size_t)NB * TSEQ * H_DIM;

  hipLaunchKernelGGL(mask_kernel, dim3(2 * NB * TSEQ / 4), dim3(256), 0, stream,
                     Q, K, qmask, kmask);
  hipLaunchKernelGGL(prepack_kernel, dim3(128), dim3(256), 0, stream,
                     Wq, Wk, Wv, kmask, WpkHi, WpkLo, AmaskF);
  hipLaunchKernelGGL(proj_kernel, dim3(H_DIM / 64, NB * TSEQ / 64, 3), dim3(256), 0, stream,
                     Q, K, V, bq, bk, bv, WpkHi, WpkLo, kmask,
                     Gqhi, Gqlo, Gkhi, Gklo, Gv);
  hipLaunchKernelGGL(attn_kernel, dim3(16 * 32 * SPLIT), dim3(256), 0, stream,
                     Gqhi, Gqlo, Gkhi, Gklo, Gv, AmaskF, Opf, Mp, Lp);
  hipLaunchKernelGGL(ln_kernel, dim3(NB * TSEQ / 4), dim3(256), 0, stream,
                     Opf, Mp, Lp, gamma, beta, qmask, out, wout);
}